// Round 14
// baseline (162.540 us; speedup 1.0000x reference)
//
#include <hip/hip_runtime.h>
#include <hip/hip_bf16.h>

// ---------------------------------------------------------------------------
// Round 14: merge m2a+m2b into one kernel — single staging phase loads BOTH
// the xt tile (43.5 KB) and t1 tile (21.76 KB, unpadded) with 16 batched
// loads/thread, one barrier, then m2a compute/stores + m2b compute/stores.
// Removes one launch boundary; t1-stage latency hides under the batch.
// Chain: prep+Z -> T -> M1 -> M2(merged).   2-rows-per-wave everywhere (r13).
// xt  : chunked  [b][ry 258][c8 8][cx 264][16B]  bf16
// t1g : px-major [b][ry 258][cx 264][32ch]       bf16
// ---------------------------------------------------------------------------

typedef __attribute__((ext_vector_type(8))) short bf16x8;
typedef __attribute__((ext_vector_type(16))) float f32x16;
typedef __attribute__((ext_vector_type(4))) unsigned int u32x4;

#define MFMA32(a,b,c) __builtin_amdgcn_mfma_f32_32x32x16_bf16(a,b,c,0,0,0)

#define XT_OFF   131072ull
#define T1_OFF   69877760ull
#define WS_NEED  104751104ull
#define ROWP     264
#define BROW     258

__device__ __forceinline__ unsigned short f2bf(float f) {
    union { __hip_bfloat16 h; unsigned short u; } cv;
    cv.h = __float2bfloat16(f);
    return cv.u;
}

__device__ __forceinline__ f32x16 zero16() {
    f32x16 z;
    #pragma unroll
    for (int i = 0; i < 16; i++) z[i] = 0.f;
    return z;
}

// fallback LDS addressing (round-3 kernel, verified)
__device__ __forceinline__ int xs_addr(int pos, int byteoff) {
    return pos * 128 + (byteoff ^ (((pos >> 2) & 7) << 4));
}
__device__ __forceinline__ int t1_addr(int pos, int byteoff) {
    return pos * 64 + (byteoff ^ ((pos & 3) << 4));
}

// ---------------------------------------------------------------------------
// prep (+pad-zeroing): blocks 0..3 = weights/biases/och, blocks 4+ = Z.
// Weight layout (bf16 elements from wb base):
//   wA   @0     [s4][g2][o32][8]        (2048)
//   wM   @2048  [tap9][s4][g2][o32][8]  (18432)
//   wAvg @20480 [s4][g2][o32][8]        (2048)
//   w1x1 @22528 [s4][g2][o32][8]        (2048)
//   wC   @24576 [tap9][s2][g2][o32][8]  (9216)
// ---------------------------------------------------------------------------
__global__ void prep_kernel(
    const float* __restrict__ c_score,
    const float* __restrict__ w_main, const float* __restrict__ bn_main,
    const float* __restrict__ w_1x1,  const float* __restrict__ bn_1x1,
    const float* __restrict__ w_3x3_1,const float* __restrict__ bn_3x3_1,
    const float* __restrict__ w_3x3_2,const float* __restrict__ bn_3x3_2,
    const float* __restrict__ w_avg,  const float* __restrict__ bn_avg_1,
    const float* __restrict__ bn_avg_2,
    int* __restrict__ och, float* __restrict__ biasb,
    __hip_bfloat16* __restrict__ wb, unsigned char* __restrict__ ws)
{
    const int t = threadIdx.x;
    const int bid = blockIdx.x;

    if (bid >= 4) {   // ---- pad zeroing ----
        int gid = (bid - 4) * 256 + t;
        unsigned short* xt = (unsigned short*)(ws + XT_OFF);
        unsigned short* t1 = (unsigned short*)(ws + T1_OFF);
        int which, c, pxid;
        if (gid < 66560) { which = 0; c = gid & 7; pxid = gid >> 3; }
        else if (gid < 99840) { int j = gid - 66560; which = 1; c = j & 3; pxid = j >> 2; }
        else return;
        int b = pxid / 1040, r = pxid - b * 1040;
        int ry, cx;
        if (r < 264)      { ry = 0;             cx = r; }
        else if (r < 528) { ry = 257;           cx = r - 264; }
        else if (r < 784) { ry = 1 + (r - 528); cx = 0; }
        else              { ry = 1 + (r - 784); cx = 257; }
        u32x4 z = {0, 0, 0, 0};
        if (which == 0) {
            size_t ch = ((size_t)(b * BROW + ry) * 8 + c) * ROWP + cx;
            *(u32x4*)(xt + ch * 8) = z;
        } else {
            size_t px = (size_t)(b * BROW + ry) * ROWP + cx;
            *(u32x4*)(t1 + px * 32 + c * 8) = z;
        }
        return;
    }

    __shared__ float ssc[128];
    __shared__ float iv[6][32];

    if (t < 128) ssc[t] = 1.f / (1.f + expf(-c_score[t]));
    if (t < 32) {
        iv[0][t] = bn_main[t]  * rsqrtf(bn_main[96+t]  + 1e-5f);
        iv[1][t] = bn_1x1[t]   * rsqrtf(bn_1x1[96+t]   + 1e-5f);
        iv[2][t] = bn_3x3_1[t] * rsqrtf(bn_3x3_1[96+t] + 1e-5f);
        iv[3][t] = bn_3x3_2[t] * rsqrtf(bn_3x3_2[96+t] + 1e-5f);
        iv[4][t] = bn_avg_1[t] * rsqrtf(bn_avg_1[96+t] + 1e-5f);
        iv[5][t] = bn_avg_2[t] * rsqrtf(bn_avg_2[96+t] + 1e-5f);
    }
    __syncthreads();

    if (bid == 0) {
        if (t < 128) {
            float sj = c_score[t];
            int r = 0;
            for (int i = 0; i < 128; i++) {
                float si = c_score[i];
                r += (si > sj) || (si == sj && i < t);
            }
            och[t] = (r < 64) ? r : -1;
        }
        if (t < 32) {
            biasb[t]     = bn_3x3_1[32+t] - bn_3x3_1[64+t]*iv[2][t];
            biasb[32+t]  = (bn_main[32+t]  - bn_main[64+t]*iv[0][t])  * ssc[t];
            biasb[64+t]  = (bn_1x1[32+t]   - bn_1x1[64+t]*iv[1][t])   * ssc[32+t];
            biasb[96+t]  = (bn_3x3_2[32+t] - bn_3x3_2[64+t]*iv[3][t]) * ssc[64+t];
            biasb[128+t] = (bn_avg_2[32+t] - bn_avg_2[64+t]*iv[5][t]) * ssc[96+t];
            float b1p = bn_avg_1[32+t] - bn_avg_1[64+t]*iv[4][t];
            biasb[160+t] = ssc[96+t] * iv[5][t] * b1p * (1.f/9.f);
        }
    } else if (bid == 1) {
        for (int i = t; i < 2048; i += 256) {
            int j = i & 7, o = (i >> 3) & 31, g = (i >> 8) & 1, s = i >> 9;
            int c = s * 16 + g * 8 + j;
            wb[i]         = __float2bfloat16(w_3x3_1[o*64+c] * iv[2][o]);
            wb[20480 + i] = __float2bfloat16(w_avg[o*64+c] * iv[4][o] * iv[5][o] * (1.f/9.f) * ssc[96+o]);
            wb[22528 + i] = __float2bfloat16(w_1x1[o*64+c] * iv[1][o] * ssc[32+o]);
        }
    } else if (bid == 2) {
        for (int i = t; i < 18432; i += 256) {
            int j = i & 7, o = (i >> 3) & 31, g = (i >> 8) & 1;
            int s = (i >> 9) & 3, tap = i >> 11;
            int c = s * 16 + g * 8 + j;
            wb[2048 + i] = __float2bfloat16(w_main[o*576 + c*9 + tap] * iv[0][o] * ssc[o]);
        }
    } else {
        for (int i = t; i < 9216; i += 256) {
            int j = i & 7, o = (i >> 3) & 31, g = (i >> 8) & 1;
            int s = (i >> 9) & 1, tap = i >> 10;
            int c = s * 16 + g * 8 + j;
            wb[24576 + i] = __float2bfloat16(w_3x3_2[o*288 + c*9 + tap] * iv[3][o] * ssc[64+o]);
        }
    }
}

// ---------------------------------------------------------------------------
// T: pure transpose x NCHW fp32 -> xt chunked bf16.  No LDS, no barrier.
// ---------------------------------------------------------------------------
__global__ __launch_bounds__(256, 8) void t_kernel(
    const float* __restrict__ x, unsigned short* __restrict__ xt)
{
    const int t = threadIdx.x;
    const int co = t >> 5, pq = t & 31;
    const int y = blockIdx.y, b = blockIdx.z;
    const int pxa = blockIdx.x * 128 + pq * 4;

    const float* xp = x + ((size_t)(b * 64 + co * 8) * 65536) + y * 256 + pxa;
    float4 f[8];
    #pragma unroll
    for (int k = 0; k < 8; k++)
        f[k] = *(const float4*)(xp + (size_t)k * 65536);

    size_t xrow = ((size_t)(b * BROW + y + 1) * 8 + co) * ROWP;   // chunk units
    #pragma unroll
    for (int u = 0; u < 4; u++) {
        u32x4 w;
        #pragma unroll
        for (int j = 0; j < 4; j++) {
            const float* a  = (const float*)&f[2*j];
            const float* c2 = (const float*)&f[2*j+1];
            w[j] = (unsigned)f2bf(a[u]) | ((unsigned)f2bf(c2[u]) << 16);
        }
        *(u32x4*)(xt + (xrow + pxa + u + 1) * 8) = w;
    }
}

// ---------------------------------------------------------------------------
// M1: t1 = BN(1x1 conv) from xt via direct global fragment loads.
// ---------------------------------------------------------------------------
__global__ __launch_bounds__(256, 8) void m1_kernel(
    const unsigned short* __restrict__ xt,
    const __hip_bfloat16* __restrict__ Wg,
    const float* __restrict__ biasb,
    unsigned short* __restrict__ t1g)
{
    const int t = threadIdx.x;
    const int lane = t & 63, wv = t >> 6;
    const int i31 = lane & 31, g = lane >> 5;
    const int y = blockIdx.y, b = blockIdx.z;
    const int px0 = blockIdx.x * 128, m0 = wv * 32;

    size_t rowb = (size_t)(b * BROW + y + 1) * 8;   // chunk-row base
    f32x16 acc = zero16();
    #pragma unroll
    for (int s = 0; s < 4; s++) {
        int ch = s * 2 + g;
        bf16x8 a  = *(const bf16x8*)(xt + ((rowb + ch) * ROWP + px0 + m0 + i31 + 1) * 8);
        bf16x8 bA = *(const bf16x8*)(Wg + (ch * 32 + i31) * 8);
        acc = MFMA32(a, bA, acc);
    }
    float bias = biasb[i31];
    size_t trow = (size_t)(b * BROW + y + 1) * ROWP;
    #pragma unroll
    for (int r = 0; r < 16; r++) {
        int px = m0 + (r & 3) + 8 * (r >> 2) + 4 * g;
        t1g[(trow + px0 + px + 1) * 32 + i31] = f2bf(acc[r] + bias);   // 2x64B/instr
    }
}

// ---------------------------------------------------------------------------
// store helpers (verified r9 epilogue; lane = och layout)
// ---------------------------------------------------------------------------
__device__ __forceinline__ void store4(float* outb, const f32x16& acc,
    const int* __restrict__ och_g, const float* __restrict__ bias32,
    int cbase, int y, int x0, int i31, int g)
{
    int rank = och_g[cbase + i31];
    if (rank < 0) return;
    float bias = bias32[i31];
    float* po = outb + (size_t)rank * 65536 + y*256 + x0 + 4*g;
    #pragma unroll
    for (int q = 0; q < 4; q++) {
        float4 v;
        v.x = acc[4*q+0] + bias;
        v.y = acc[4*q+1] + bias;
        v.z = acc[4*q+2] + bias;
        v.w = acc[4*q+3] + bias;
        *(float4*)(po + 8*q) = v;
    }
}

__device__ __forceinline__ void store4avg(float* outb, const f32x16& acc,
    const int* __restrict__ och_g, const float* __restrict__ biasb,
    int y, int x0, int i31, int g)
{
    int rank = och_g[96 + i31];
    if (rank < 0) return;
    float t2b = biasb[128 + i31];
    float b19 = biasb[160 + i31];
    float cy = 3.f - (float)(y == 0) - (float)(y == 255);
    float* po = outb + (size_t)rank * 65536 + y*256 + x0 + 4*g;
    #pragma unroll
    for (int q = 0; q < 4; q++) {
        float4 v;
        #pragma unroll
        for (int u = 0; u < 4; u++) {
            int gx = x0 + 4*g + 8*q + u;
            float cx = 3.f - (float)(gx == 0) - (float)(gx == 255);
            ((float*)&v)[u] = acc[4*q+u] + t2b + b19 * (cy * cx);
        }
        *(float4*)(po + 8*q) = v;
    }
}

// ---------------------------------------------------------------------------
// M2 (merged): stage xt tile + t1 tile (one batch, one barrier), then
// m2a compute (main/1x1/avg) + stores, then m2b compute (3x3@t1) + stores.
// LDS: xs [c8][10][34] 43520 B + t1s [c4][10][34] 21760 B = 65280 B.
// grid (8,32,8), 256 thr / 4 waves; wave wv -> output rows y0+2wv, y0+2wv+1.
// ---------------------------------------------------------------------------
__global__ __launch_bounds__(256, 2) void m2_kernel(
    const unsigned short* __restrict__ xt,
    const unsigned short* __restrict__ t1g,
    const __hip_bfloat16* __restrict__ Wg,
    const int* __restrict__ och_g,
    const float* __restrict__ biasb,
    float* __restrict__ out)
{
    __shared__ __align__(16) unsigned short xs[2720 * 8];    // 43520 B
    __shared__ __align__(16) unsigned short t1s[1360 * 8];   // 21760 B

    const int t = threadIdx.x;
    const int lane = t & 63, wv = t >> 6;
    const int i31 = lane & 31, g = lane >> 5;
    const int x0 = blockIdx.x * 32, y0 = blockIdx.y * 8;
    const int b = blockIdx.z;

    // ---- stage both tiles: 4080 chunks, 16 batched loads/thread ----
    {
        u32x4 tmp[16];
        int   jj[16];
        #pragma unroll
        for (int i = 0; i < 16; i++) {
            int j = t + i * 256;
            if (j > 4079) j = 4079;
            jj[i] = j;
            if (j < 2720) {
                int c = j / 340, rem = j - c * 340, r = rem / 34, p = rem - r * 34;
                size_t src = ((size_t)(b * BROW + y0 + r) * 8 + c) * ROWP + x0 + p;
                tmp[i] = *(const u32x4*)(xt + src * 8);
            } else {
                int j2 = j - 2720;
                int c4 = j2 & 3, pr = j2 >> 2;
                int r = pr / 34, p = pr - r * 34;
                size_t src = ((size_t)(b * BROW + y0 + r) * ROWP + x0 + p) * 32 + c4 * 8;
                tmp[i] = *(const u32x4*)(t1g + src);
            }
        }
        #pragma unroll
        for (int i = 0; i < 16; i++) {
            int j = jj[i];
            if (j < 2720) *(u32x4*)(xs + (size_t)j * 8) = tmp[i];
            else {
                int j2 = j - 2720;
                int c4 = j2 & 3, pr = j2 >> 2;
                int r = pr / 34, p = pr - r * 34;
                *(u32x4*)(t1s + (size_t)(c4 * 340 + r * 34 + p) * 8) = tmp[i];
            }
        }
    }
    __syncthreads();

    const int y_0 = y0 + 2 * wv, y_1 = y_0 + 1;      // output rows
    const int r0 = 2 * wv + 1, r1 = r0 + 1;          // halo rows
    float* outb = out + (size_t)b * (64 * 65536);

    // ---- m2a: main 3x3 + avg-as-3x3 + 1x1(center), 2 rows/wave ----
    {
        f32x16 aM0 = zero16(), aM1 = zero16();
        f32x16 aG0 = zero16(), aG1 = zero16();
        f32x16 aX0 = zero16(), aX1 = zero16();
        bf16x8 bg[4], bx[4];
        #pragma unroll
        for (int s = 0; s < 4; s++) {
            bg[s] = *(const bf16x8*)(Wg + 20480 + ((s*2+g)*32 + i31) * 8);
            bx[s] = *(const bf16x8*)(Wg + 22528 + ((s*2+g)*32 + i31) * 8);
        }
        #pragma unroll
        for (int tap = 0; tap < 9; tap++) {
            int dy = tap / 3 - 1, dx = tap - (tap / 3) * 3 - 1;
            int pbase = i31 + dx + 1;
            #pragma unroll
            for (int s = 0; s < 4; s++) {
                bf16x8 bm = *(const bf16x8*)(Wg + 2048 + (((tap*4+s)*2+g)*32 + i31) * 8);
                bf16x8 a0 = *(const bf16x8*)(xs + (size_t)(((s*2+g) * 10 + r0 + dy) * 34 + pbase) * 8);
                bf16x8 a1 = *(const bf16x8*)(xs + (size_t)(((s*2+g) * 10 + r1 + dy) * 34 + pbase) * 8);
                aM0 = MFMA32(a0, bm, aM0);
                aM1 = MFMA32(a1, bm, aM1);
                aG0 = MFMA32(a0, bg[s], aG0);
                aG1 = MFMA32(a1, bg[s], aG1);
                if (tap == 4) {
                    aX0 = MFMA32(a0, bx[s], aX0);
                    aX1 = MFMA32(a1, bx[s], aX1);
                }
            }
        }
        store4(outb, aM0, och_g, biasb + 32, 0,  y_0, x0, i31, g);  // main -> [0,32)
        store4(outb, aM1, och_g, biasb + 32, 0,  y_1, x0, i31, g);
        store4(outb, aX0, och_g, biasb + 64, 32, y_0, x0, i31, g);  // 1x1  -> [32,64)
        store4(outb, aX1, och_g, biasb + 64, 32, y_1, x0, i31, g);
        store4avg(outb, aG0, och_g, biasb, y_0, x0, i31, g);        // avg  -> [96,128)
        store4avg(outb, aG1, och_g, biasb, y_1, x0, i31, g);
    }

    // ---- m2b: 3x3 conv on t1s, 2 rows/wave ----
    {
        f32x16 aC0 = zero16(), aC1 = zero16();
        #pragma unroll
        for (int tap = 0; tap < 9; tap++) {
            int dy = tap / 3 - 1, dx = tap - (tap / 3) * 3 - 1;
            int pbase = i31 + dx + 1;
            #pragma unroll
            for (int s = 0; s < 2; s++) {
                bf16x8 bc = *(const bf16x8*)(Wg + 24576 + (((tap*2+s)*2+g)*32 + i31) * 8);
                bf16x8 a0 = *(const bf16x8*)(t1s + (size_t)((s*2+g) * 340 + (r0 + dy) * 34 + pbase) * 8);
                bf16x8 a1 = *(const bf16x8*)(t1s + (size_t)((s*2+g) * 340 + (r1 + dy) * 34 + pbase) * 8);
                aC0 = MFMA32(a0, bc, aC0);
                aC1 = MFMA32(a1, bc, aC1);
            }
        }
        store4(outb, aC0, och_g, biasb + 96, 64, y_0, x0, i31, g);  // 3x3 -> [64,96)
        store4(outb, aC1, och_g, biasb + 96, 64, y_1, x0, i31, g);
    }
}

// ---------------------------------------------------------------------------
// Fallback: round-3 single fused kernel (r8 weight addressing) for small ws.
// ---------------------------------------------------------------------------
__global__ __launch_bounds__(512, 4) void fused_fallback(
    const float* __restrict__ x,
    const __hip_bfloat16* __restrict__ Wg,
    const int* __restrict__ och_g,
    const float* __restrict__ biasb,
    float* __restrict__ out)
{
    __shared__ __align__(16) unsigned char xs[400 * 128];
    __shared__ __align__(16) unsigned char t1s[340 * 64];

    const int t = threadIdx.x;
    const int lane = t & 63, wv = t >> 6;
    const int i31 = lane & 31, g = lane >> 5;
    const int x0 = blockIdx.x * 32, y0 = blockIdx.y * 8;
    const int b = blockIdx.z;

    const float* xb = x + (size_t)b * (64 * 65536);
    for (int j = t; j < 800; j += 512) {
        int co = j / 100;
        int rem = j - co * 100;
        int row = rem / 10, xq = rem - row * 10;
        int gy = y0 - 1 + row;
        int gx0 = x0 - 4 + 4 * xq;
        bool ok = ((unsigned)gy < 256u) && ((unsigned)gx0 <= 252u);
        const float* p = xb + (size_t)(co * 8) * 65536 + (size_t)gy * 256 + gx0;
        float4 f0 = {0,0,0,0}, f1 = {0,0,0,0}, f2 = {0,0,0,0}, f3 = {0,0,0,0};
        float4 f4 = {0,0,0,0}, f5 = {0,0,0,0}, f6 = {0,0,0,0}, f7 = {0,0,0,0};
        if (ok) {
            f0 = *(const float4*)(p);
            f1 = *(const float4*)(p + 65536);
            f2 = *(const float4*)(p + 131072);
            f3 = *(const float4*)(p + 196608);
            f4 = *(const float4*)(p + 262144);
            f5 = *(const float4*)(p + 327680);
            f6 = *(const float4*)(p + 393216);
            f7 = *(const float4*)(p + 458752);
        }
        const float* fv[8] = {(const float*)&f0, (const float*)&f1, (const float*)&f2,
                              (const float*)&f3, (const float*)&f4, (const float*)&f5,
                              (const float*)&f6, (const float*)&f7};
        #pragma unroll
        for (int u = 0; u < 4; u++) {
            int pos = row * 40 + 4 * xq + u;
            u32x4 w;
            w[0] = (unsigned)f2bf(fv[0][u]) | ((unsigned)f2bf(fv[1][u]) << 16);
            w[1] = (unsigned)f2bf(fv[2][u]) | ((unsigned)f2bf(fv[3][u]) << 16);
            w[2] = (unsigned)f2bf(fv[4][u]) | ((unsigned)f2bf(fv[5][u]) << 16);
            w[3] = (unsigned)f2bf(fv[6][u]) | ((unsigned)f2bf(fv[7][u]) << 16);
            *(u32x4*)(xs + xs_addr(pos, co * 16)) = w;
        }
    }
    __syncthreads();

    {
        bf16x8 bA[4];
        #pragma unroll
        for (int s = 0; s < 4; s++)
            bA[s] = *(const bf16x8*)(Wg + ((s*2+g)*32 + i31) * 8);
        float biasA = biasb[i31];
        for (int mt = wv; mt < 11; mt += 8) {
            int m0 = mt * 32;
            f32x16 acc = zero16();
            int qr = m0 + i31; if (qr > 339) qr = 339;
            int hy = qr / 34, hx = qr - hy * 34;
            int pos = hy * 40 + hx + 3;
            #pragma unroll
            for (int s = 0; s < 4; s++) {
                bf16x8 a = *(const bf16x8*)(xs + xs_addr(pos, s * 32 + g * 16));
                acc = MFMA32(a, bA[s], acc);
            }
            #pragma unroll
            for (int r = 0; r < 16; r++) {
                int q = m0 + (r & 3) + 8 * (r >> 2) + 4 * g;
                if (q < 340) {
                    int hy2 = q / 34, hx2 = q - hy2 * 34;
                    int gy = y0 - 1 + hy2, gx = x0 - 1 + hx2;
                    bool valid = ((unsigned)gy < 256u) && ((unsigned)gx < 256u);
                    float vv = valid ? (acc[r] + biasA) : 0.f;
                    *(unsigned short*)(t1s + t1_addr(q, i31 * 2)) = f2bf(vv);
                }
            }
        }
    }
    __syncthreads();

    float* outb = out + (size_t)b * (64 * 65536);
    const int y = y0 + wv;

    f32x16 aM = zero16(), aG = zero16(), aX = zero16();
    {
        bf16x8 bg[4], bx[4];
        #pragma unroll
        for (int s = 0; s < 4; s++) {
            bg[s] = *(const bf16x8*)(Wg + 20480 + ((s*2+g)*32 + i31) * 8);
            bx[s] = *(const bf16x8*)(Wg + 22528 + ((s*2+g)*32 + i31) * 8);
        }
        for (int tap = 0; tap < 9; tap++) {
            int dy = tap / 3 - 1, dx = tap - (tap / 3) * 3 - 1;
            int pos = (wv + 1 + dy) * 40 + 4 + dx + i31;
            #pragma unroll
            for (int s = 0; s < 4; s++) {
                bf16x8 bm = *(const bf16x8*)(Wg + 2048 + (((tap*4+s)*2+g)*32 + i31) * 8);
                bf16x8 a = *(const bf16x8*)(xs + xs_addr(pos, s * 32 + g * 16));
                aM = MFMA32(a, bm, aM);
                aG = MFMA32(a, bg[s], aG);
                if (tap == 4) aX = MFMA32(a, bx[s], aX);
            }
        }
    }
    store4(outb, aM, och_g, biasb + 32, 0,  y, x0, i31, g);
    store4(outb, aX, och_g, biasb + 64, 32, y, x0, i31, g);
    store4avg(outb, aG, och_g, biasb, y, x0, i31, g);

    f32x16 aC = zero16();
    for (int tap = 0; tap < 9; tap++) {
        int dy = tap / 3 - 1, dx = tap - (tap / 3) * 3 - 1;
        int q = (wv + 1 + dy) * 34 + 1 + dx + i31;
        #pragma unroll
        for (int s = 0; s < 2; s++) {
            bf16x8 bc = *(const bf16x8*)(Wg + 24576 + (((tap*2+s)*2+g)*32 + i31) * 8);
            bf16x8 a = *(const bf16x8*)(t1s + t1_addr(q, s * 32 + g * 16));
            aC = MFMA32(a, bc, aC);
        }
    }
    store4(outb, aC, och_g, biasb + 96, 64, y, x0, i31, g);
}

// ---------------------------------------------------------------------------
extern "C" void kernel_launch(void* const* d_in, const int* in_sizes, int n_in,
                              void* d_out, int out_size, void* d_ws, size_t ws_size,
                              hipStream_t stream)
{
    const float* x        = (const float*)d_in[0];
    const float* w_main   = (const float*)d_in[1];
    const float* bn_main  = (const float*)d_in[2];
    const float* w_1x1    = (const float*)d_in[3];
    const float* bn_1x1   = (const float*)d_in[4];
    const float* w_3x3_1  = (const float*)d_in[5];
    const float* bn_3x3_1 = (const float*)d_in[6];
    const float* w_3x3_2  = (const float*)d_in[7];
    const float* bn_3x3_2 = (const float*)d_in[8];
    const float* w_avg    = (const float*)d_in[9];
    const float* bn_avg_1 = (const float*)d_in[10];
    const float* bn_avg_2 = (const float*)d_in[11];
    const float* c_score  = (const float*)d_in[12];

    int*   och   = (int*)d_ws;
    float* biasb = (float*)((char*)d_ws + 512);
    __hip_bfloat16* wb = (__hip_bfloat16*)((char*)d_ws + 2048);

    const bool big = (ws_size >= WS_NEED);
    prep_kernel<<<big ? 394 : 4, 256, 0, stream>>>(
        c_score, w_main, bn_main, w_1x1, bn_1x1,
        w_3x3_1, bn_3x3_1, w_3x3_2, bn_3x3_2, w_avg, bn_avg_1, bn_avg_2,
        och, biasb, wb, (unsigned char*)d_ws);

    if (big) {
        unsigned short* xt  = (unsigned short*)((char*)d_ws + XT_OFF);
        unsigned short* t1g = (unsigned short*)((char*)d_ws + T1_OFF);

        t_kernel<<<dim3(2, 256, 8), 256, 0, stream>>>(x, xt);
        m1_kernel<<<dim3(2, 256, 8), 256, 0, stream>>>(xt, wb, biasb, t1g);
        m2_kernel<<<dim3(8, 32, 8), 256, 0, stream>>>(
            xt, t1g, wb, och, biasb, (float*)d_out);
    } else {
        fused_fallback<<<dim3(8, 32, 8), 512, 0, stream>>>(
            x, wb, och, biasb, (float*)d_out);
    }
}

// Round 15
// 143.555 us; speedup vs baseline: 1.1323x; 1.1323x over previous
//
#include <hip/hip_runtime.h>
#include <hip/hip_bf16.h>

// ---------------------------------------------------------------------------
// Round 15: r13 (147.4us verified) with m2a+m2b fused as ONE DISPATCH but
// SEPARATE block paths (grid.z=16: z<8 -> m2a, z>=8 -> m2b).  Each path keeps
// its r13 staging, LDS layout (incl. m2b's 35-pad), and occupancy; only the
// launch boundary between them is removed.
// Chain: prep+Z -> T -> M1 -> M2AB(fused dispatch).
// xt  : chunked  [b][ry 258][c8 8][cx 264][16B]  bf16
// t1g : px-major [b][ry 258][cx 264][32ch]       bf16
// ---------------------------------------------------------------------------

typedef __attribute__((ext_vector_type(8))) short bf16x8;
typedef __attribute__((ext_vector_type(16))) float f32x16;
typedef __attribute__((ext_vector_type(4))) unsigned int u32x4;

#define MFMA32(a,b,c) __builtin_amdgcn_mfma_f32_32x32x16_bf16(a,b,c,0,0,0)

#define XT_OFF   131072ull
#define T1_OFF   69877760ull
#define WS_NEED  104751104ull
#define ROWP     264
#define BROW     258

__device__ __forceinline__ unsigned short f2bf(float f) {
    union { __hip_bfloat16 h; unsigned short u; } cv;
    cv.h = __float2bfloat16(f);
    return cv.u;
}

__device__ __forceinline__ f32x16 zero16() {
    f32x16 z;
    #pragma unroll
    for (int i = 0; i < 16; i++) z[i] = 0.f;
    return z;
}

// fallback LDS addressing (round-3 kernel, verified)
__device__ __forceinline__ int xs_addr(int pos, int byteoff) {
    return pos * 128 + (byteoff ^ (((pos >> 2) & 7) << 4));
}
__device__ __forceinline__ int t1_addr(int pos, int byteoff) {
    return pos * 64 + (byteoff ^ ((pos & 3) << 4));
}

// ---------------------------------------------------------------------------
// prep (+pad-zeroing): blocks 0..3 = weights/biases/och, blocks 4+ = Z.
// Weight layout (bf16 elements from wb base):
//   wA   @0     [s4][g2][o32][8]        (2048)
//   wM   @2048  [tap9][s4][g2][o32][8]  (18432)
//   wAvg @20480 [s4][g2][o32][8]        (2048)
//   w1x1 @22528 [s4][g2][o32][8]        (2048)
//   wC   @24576 [tap9][s2][g2][o32][8]  (9216)
// ---------------------------------------------------------------------------
__global__ void prep_kernel(
    const float* __restrict__ c_score,
    const float* __restrict__ w_main, const float* __restrict__ bn_main,
    const float* __restrict__ w_1x1,  const float* __restrict__ bn_1x1,
    const float* __restrict__ w_3x3_1,const float* __restrict__ bn_3x3_1,
    const float* __restrict__ w_3x3_2,const float* __restrict__ bn_3x3_2,
    const float* __restrict__ w_avg,  const float* __restrict__ bn_avg_1,
    const float* __restrict__ bn_avg_2,
    int* __restrict__ och, float* __restrict__ biasb,
    __hip_bfloat16* __restrict__ wb, unsigned char* __restrict__ ws)
{
    const int t = threadIdx.x;
    const int bid = blockIdx.x;

    if (bid >= 4) {   // ---- pad zeroing ----
        int gid = (bid - 4) * 256 + t;
        unsigned short* xt = (unsigned short*)(ws + XT_OFF);
        unsigned short* t1 = (unsigned short*)(ws + T1_OFF);
        int which, c, pxid;
        if (gid < 66560) { which = 0; c = gid & 7; pxid = gid >> 3; }
        else if (gid < 99840) { int j = gid - 66560; which = 1; c = j & 3; pxid = j >> 2; }
        else return;
        int b = pxid / 1040, r = pxid - b * 1040;
        int ry, cx;
        if (r < 264)      { ry = 0;             cx = r; }
        else if (r < 528) { ry = 257;           cx = r - 264; }
        else if (r < 784) { ry = 1 + (r - 528); cx = 0; }
        else              { ry = 1 + (r - 784); cx = 257; }
        u32x4 z = {0, 0, 0, 0};
        if (which == 0) {
            size_t ch = ((size_t)(b * BROW + ry) * 8 + c) * ROWP + cx;
            *(u32x4*)(xt + ch * 8) = z;
        } else {
            size_t px = (size_t)(b * BROW + ry) * ROWP + cx;
            *(u32x4*)(t1 + px * 32 + c * 8) = z;
        }
        return;
    }

    __shared__ float ssc[128];
    __shared__ float iv[6][32];

    if (t < 128) ssc[t] = 1.f / (1.f + expf(-c_score[t]));
    if (t < 32) {
        iv[0][t] = bn_main[t]  * rsqrtf(bn_main[96+t]  + 1e-5f);
        iv[1][t] = bn_1x1[t]   * rsqrtf(bn_1x1[96+t]   + 1e-5f);
        iv[2][t] = bn_3x3_1[t] * rsqrtf(bn_3x3_1[96+t] + 1e-5f);
        iv[3][t] = bn_3x3_2[t] * rsqrtf(bn_3x3_2[96+t] + 1e-5f);
        iv[4][t] = bn_avg_1[t] * rsqrtf(bn_avg_1[96+t] + 1e-5f);
        iv[5][t] = bn_avg_2[t] * rsqrtf(bn_avg_2[96+t] + 1e-5f);
    }
    __syncthreads();

    if (bid == 0) {
        if (t < 128) {
            float sj = c_score[t];
            int r = 0;
            for (int i = 0; i < 128; i++) {
                float si = c_score[i];
                r += (si > sj) || (si == sj && i < t);
            }
            och[t] = (r < 64) ? r : -1;
        }
        if (t < 32) {
            biasb[t]     = bn_3x3_1[32+t] - bn_3x3_1[64+t]*iv[2][t];
            biasb[32+t]  = (bn_main[32+t]  - bn_main[64+t]*iv[0][t])  * ssc[t];
            biasb[64+t]  = (bn_1x1[32+t]   - bn_1x1[64+t]*iv[1][t])   * ssc[32+t];
            biasb[96+t]  = (bn_3x3_2[32+t] - bn_3x3_2[64+t]*iv[3][t]) * ssc[64+t];
            biasb[128+t] = (bn_avg_2[32+t] - bn_avg_2[64+t]*iv[5][t]) * ssc[96+t];
            float b1p = bn_avg_1[32+t] - bn_avg_1[64+t]*iv[4][t];
            biasb[160+t] = ssc[96+t] * iv[5][t] * b1p * (1.f/9.f);
        }
    } else if (bid == 1) {
        for (int i = t; i < 2048; i += 256) {
            int j = i & 7, o = (i >> 3) & 31, g = (i >> 8) & 1, s = i >> 9;
            int c = s * 16 + g * 8 + j;
            wb[i]         = __float2bfloat16(w_3x3_1[o*64+c] * iv[2][o]);
            wb[20480 + i] = __float2bfloat16(w_avg[o*64+c] * iv[4][o] * iv[5][o] * (1.f/9.f) * ssc[96+o]);
            wb[22528 + i] = __float2bfloat16(w_1x1[o*64+c] * iv[1][o] * ssc[32+o]);
        }
    } else if (bid == 2) {
        for (int i = t; i < 18432; i += 256) {
            int j = i & 7, o = (i >> 3) & 31, g = (i >> 8) & 1;
            int s = (i >> 9) & 3, tap = i >> 11;
            int c = s * 16 + g * 8 + j;
            wb[2048 + i] = __float2bfloat16(w_main[o*576 + c*9 + tap] * iv[0][o] * ssc[o]);
        }
    } else {
        for (int i = t; i < 9216; i += 256) {
            int j = i & 7, o = (i >> 3) & 31, g = (i >> 8) & 1;
            int s = (i >> 9) & 1, tap = i >> 10;
            int c = s * 16 + g * 8 + j;
            wb[24576 + i] = __float2bfloat16(w_3x3_2[o*288 + c*9 + tap] * iv[3][o] * ssc[64+o]);
        }
    }
}

// ---------------------------------------------------------------------------
// T: pure transpose x NCHW fp32 -> xt chunked bf16.  No LDS, no barrier.
// ---------------------------------------------------------------------------
__global__ __launch_bounds__(256, 8) void t_kernel(
    const float* __restrict__ x, unsigned short* __restrict__ xt)
{
    const int t = threadIdx.x;
    const int co = t >> 5, pq = t & 31;
    const int y = blockIdx.y, b = blockIdx.z;
    const int pxa = blockIdx.x * 128 + pq * 4;

    const float* xp = x + ((size_t)(b * 64 + co * 8) * 65536) + y * 256 + pxa;
    float4 f[8];
    #pragma unroll
    for (int k = 0; k < 8; k++)
        f[k] = *(const float4*)(xp + (size_t)k * 65536);

    size_t xrow = ((size_t)(b * BROW + y + 1) * 8 + co) * ROWP;   // chunk units
    #pragma unroll
    for (int u = 0; u < 4; u++) {
        u32x4 w;
        #pragma unroll
        for (int j = 0; j < 4; j++) {
            const float* a  = (const float*)&f[2*j];
            const float* c2 = (const float*)&f[2*j+1];
            w[j] = (unsigned)f2bf(a[u]) | ((unsigned)f2bf(c2[u]) << 16);
        }
        *(u32x4*)(xt + (xrow + pxa + u + 1) * 8) = w;
    }
}

// ---------------------------------------------------------------------------
// M1: t1 = BN(1x1 conv) from xt via direct global fragment loads.
// ---------------------------------------------------------------------------
__global__ __launch_bounds__(256, 8) void m1_kernel(
    const unsigned short* __restrict__ xt,
    const __hip_bfloat16* __restrict__ Wg,
    const float* __restrict__ biasb,
    unsigned short* __restrict__ t1g)
{
    const int t = threadIdx.x;
    const int lane = t & 63, wv = t >> 6;
    const int i31 = lane & 31, g = lane >> 5;
    const int y = blockIdx.y, b = blockIdx.z;
    const int px0 = blockIdx.x * 128, m0 = wv * 32;

    size_t rowb = (size_t)(b * BROW + y + 1) * 8;   // chunk-row base
    f32x16 acc = zero16();
    #pragma unroll
    for (int s = 0; s < 4; s++) {
        int ch = s * 2 + g;
        bf16x8 a  = *(const bf16x8*)(xt + ((rowb + ch) * ROWP + px0 + m0 + i31 + 1) * 8);
        bf16x8 bA = *(const bf16x8*)(Wg + (ch * 32 + i31) * 8);
        acc = MFMA32(a, bA, acc);
    }
    float bias = biasb[i31];
    size_t trow = (size_t)(b * BROW + y + 1) * ROWP;
    #pragma unroll
    for (int r = 0; r < 16; r++) {
        int px = m0 + (r & 3) + 8 * (r >> 2) + 4 * g;
        t1g[(trow + px0 + px + 1) * 32 + i31] = f2bf(acc[r] + bias);   // 2x64B/instr
    }
}

// ---------------------------------------------------------------------------
// store helpers (verified r9 epilogue; lane = och layout)
// ---------------------------------------------------------------------------
__device__ __forceinline__ void store4(float* outb, const f32x16& acc,
    const int* __restrict__ och_g, const float* __restrict__ bias32,
    int cbase, int y, int x0, int i31, int g)
{
    int rank = och_g[cbase + i31];
    if (rank < 0) return;
    float bias = bias32[i31];
    float* po = outb + (size_t)rank * 65536 + y*256 + x0 + 4*g;
    #pragma unroll
    for (int q = 0; q < 4; q++) {
        float4 v;
        v.x = acc[4*q+0] + bias;
        v.y = acc[4*q+1] + bias;
        v.z = acc[4*q+2] + bias;
        v.w = acc[4*q+3] + bias;
        *(float4*)(po + 8*q) = v;
    }
}

__device__ __forceinline__ void store4avg(float* outb, const f32x16& acc,
    const int* __restrict__ och_g, const float* __restrict__ biasb,
    int y, int x0, int i31, int g)
{
    int rank = och_g[96 + i31];
    if (rank < 0) return;
    float t2b = biasb[128 + i31];
    float b19 = biasb[160 + i31];
    float cy = 3.f - (float)(y == 0) - (float)(y == 255);
    float* po = outb + (size_t)rank * 65536 + y*256 + x0 + 4*g;
    #pragma unroll
    for (int q = 0; q < 4; q++) {
        float4 v;
        #pragma unroll
        for (int u = 0; u < 4; u++) {
            int gx = x0 + 4*g + 8*q + u;
            float cx = 3.f - (float)(gx == 0) - (float)(gx == 255);
            ((float*)&v)[u] = acc[4*q+u] + t2b + b19 * (cy * cx);
        }
        *(float4*)(po + 8*q) = v;
    }
}

// ---------------------------------------------------------------------------
// M2AB: one dispatch, two block paths (r13's kernels verbatim).
//   blockIdx.z <  8 : m2a path, b = z      (LDS 43520 B, [c8][10][34])
//   blockIdx.z >= 8 : m2b path, b = z - 8  (LDS 22400 B, [c4][10][35] padded)
// grid (8,32,16), 256 thr / 4 waves; wave -> 2 output rows.
// ---------------------------------------------------------------------------
__global__ __launch_bounds__(256, 2) void m2ab_kernel(
    const unsigned short* __restrict__ xt,
    const unsigned short* __restrict__ t1g,
    const __hip_bfloat16* __restrict__ Wg,
    const int* __restrict__ och_g,
    const float* __restrict__ biasb,
    float* __restrict__ out)
{
    __shared__ __align__(16) unsigned char smem[43520];

    const int t = threadIdx.x;
    const int lane = t & 63, wv = t >> 6;
    const int i31 = lane & 31, g = lane >> 5;
    const int x0 = blockIdx.x * 32, y0 = blockIdx.y * 8;
    const int zz = blockIdx.z;

    const int y_0 = y0 + 2 * wv, y_1 = y_0 + 1;      // output rows
    const int r0 = 2 * wv + 1, r1 = r0 + 1;          // halo rows

    if (zz < 8) {
        // ================= m2a path =================
        const int b = zz;
        unsigned short* xs = (unsigned short*)smem;   // [c8][10][34] chunks
        {
            u32x4 tmp[11];
            int   jj[11];
            #pragma unroll
            for (int i = 0; i < 11; i++) {
                int j = t + i * 256;
                if (j > 2719) j = 2719;
                jj[i] = j;
                int c = j / 340, rem = j - c * 340, r = rem / 34, p = rem - r * 34;
                size_t src = ((size_t)(b * BROW + y0 + r) * 8 + c) * ROWP + x0 + p;
                tmp[i] = *(const u32x4*)(xt + src * 8);
            }
            #pragma unroll
            for (int i = 0; i < 11; i++)
                *(u32x4*)(xs + (size_t)jj[i] * 8) = tmp[i];
        }
        __syncthreads();

        float* outb = out + (size_t)b * (64 * 65536);
        f32x16 aM0 = zero16(), aM1 = zero16();
        f32x16 aG0 = zero16(), aG1 = zero16();
        f32x16 aX0 = zero16(), aX1 = zero16();
        {
            bf16x8 bg[4], bx[4];
            #pragma unroll
            for (int s = 0; s < 4; s++) {
                bg[s] = *(const bf16x8*)(Wg + 20480 + ((s*2+g)*32 + i31) * 8);
                bx[s] = *(const bf16x8*)(Wg + 22528 + ((s*2+g)*32 + i31) * 8);
            }
            #pragma unroll
            for (int tap = 0; tap < 9; tap++) {
                int dy = tap / 3 - 1, dx = tap - (tap / 3) * 3 - 1;
                int pbase = i31 + dx + 1;
                #pragma unroll
                for (int s = 0; s < 4; s++) {
                    bf16x8 bm = *(const bf16x8*)(Wg + 2048 + (((tap*4+s)*2+g)*32 + i31) * 8);
                    bf16x8 a0 = *(const bf16x8*)(xs + (size_t)(((s*2+g) * 10 + r0 + dy) * 34 + pbase) * 8);
                    bf16x8 a1 = *(const bf16x8*)(xs + (size_t)(((s*2+g) * 10 + r1 + dy) * 34 + pbase) * 8);
                    aM0 = MFMA32(a0, bm, aM0);
                    aM1 = MFMA32(a1, bm, aM1);
                    aG0 = MFMA32(a0, bg[s], aG0);
                    aG1 = MFMA32(a1, bg[s], aG1);
                    if (tap == 4) {
                        aX0 = MFMA32(a0, bx[s], aX0);
                        aX1 = MFMA32(a1, bx[s], aX1);
                    }
                }
            }
        }
        store4(outb, aM0, och_g, biasb + 32, 0,  y_0, x0, i31, g);  // main -> [0,32)
        store4(outb, aM1, och_g, biasb + 32, 0,  y_1, x0, i31, g);
        store4(outb, aX0, och_g, biasb + 64, 32, y_0, x0, i31, g);  // 1x1  -> [32,64)
        store4(outb, aX1, och_g, biasb + 64, 32, y_1, x0, i31, g);
        store4avg(outb, aG0, och_g, biasb, y_0, x0, i31, g);        // avg  -> [96,128)
        store4avg(outb, aG1, och_g, biasb, y_1, x0, i31, g);
    } else {
        // ================= m2b path =================
        const int b = zz - 8;
        unsigned short* t1s = (unsigned short*)smem;  // [c4][10][35] chunks (padded)
        #pragma unroll
        for (int i = 0; i < 6; i++) {
            int j = t + i * 256;
            if (j > 1359) j = 1359;
            int c4 = j & 3, pr = j >> 2;
            int r = pr / 34, p = pr - r * 34;
            size_t src = ((size_t)(b * BROW + y0 + r) * ROWP + x0 + p) * 32 + c4 * 8;
            int ci = c4 * 350 + r * 35 + p;
            *(u32x4*)(t1s + (size_t)ci * 8) = *(const u32x4*)(t1g + src);
        }
        __syncthreads();

        float* outb = out + (size_t)b * (64 * 65536);
        f32x16 aC0 = zero16(), aC1 = zero16();
        #pragma unroll
        for (int tap = 0; tap < 9; tap++) {
            int dy = tap / 3 - 1, dx = tap - (tap / 3) * 3 - 1;
            int pbase = i31 + dx + 1;
            #pragma unroll
            for (int s = 0; s < 2; s++) {
                bf16x8 bc = *(const bf16x8*)(Wg + 24576 + (((tap*2+s)*2+g)*32 + i31) * 8);
                bf16x8 a0 = *(const bf16x8*)(t1s + (size_t)((s*2+g) * 350 + (r0 + dy) * 35 + pbase) * 8);
                bf16x8 a1 = *(const bf16x8*)(t1s + (size_t)((s*2+g) * 350 + (r1 + dy) * 35 + pbase) * 8);
                aC0 = MFMA32(a0, bc, aC0);
                aC1 = MFMA32(a1, bc, aC1);
            }
        }
        store4(outb, aC0, och_g, biasb + 96, 64, y_0, x0, i31, g);  // 3x3 -> [64,96)
        store4(outb, aC1, och_g, biasb + 96, 64, y_1, x0, i31, g);
    }
}

// ---------------------------------------------------------------------------
// Fallback: round-3 single fused kernel (r8 weight addressing) for small ws.
// ---------------------------------------------------------------------------
__global__ __launch_bounds__(512, 4) void fused_fallback(
    const float* __restrict__ x,
    const __hip_bfloat16* __restrict__ Wg,
    const int* __restrict__ och_g,
    const float* __restrict__ biasb,
    float* __restrict__ out)
{
    __shared__ __align__(16) unsigned char xs[400 * 128];
    __shared__ __align__(16) unsigned char t1s[340 * 64];

    const int t = threadIdx.x;
    const int lane = t & 63, wv = t >> 6;
    const int i31 = lane & 31, g = lane >> 5;
    const int x0 = blockIdx.x * 32, y0 = blockIdx.y * 8;
    const int b = blockIdx.z;

    const float* xb = x + (size_t)b * (64 * 65536);
    for (int j = t; j < 800; j += 512) {
        int co = j / 100;
        int rem = j - co * 100;
        int row = rem / 10, xq = rem - row * 10;
        int gy = y0 - 1 + row;
        int gx0 = x0 - 4 + 4 * xq;
        bool ok = ((unsigned)gy < 256u) && ((unsigned)gx0 <= 252u);
        const float* p = xb + (size_t)(co * 8) * 65536 + (size_t)gy * 256 + gx0;
        float4 f0 = {0,0,0,0}, f1 = {0,0,0,0}, f2 = {0,0,0,0}, f3 = {0,0,0,0};
        float4 f4 = {0,0,0,0}, f5 = {0,0,0,0}, f6 = {0,0,0,0}, f7 = {0,0,0,0};
        if (ok) {
            f0 = *(const float4*)(p);
            f1 = *(const float4*)(p + 65536);
            f2 = *(const float4*)(p + 131072);
            f3 = *(const float4*)(p + 196608);
            f4 = *(const float4*)(p + 262144);
            f5 = *(const float4*)(p + 327680);
            f6 = *(const float4*)(p + 393216);
            f7 = *(const float4*)(p + 458752);
        }
        const float* fv[8] = {(const float*)&f0, (const float*)&f1, (const float*)&f2,
                              (const float*)&f3, (const float*)&f4, (const float*)&f5,
                              (const float*)&f6, (const float*)&f7};
        #pragma unroll
        for (int u = 0; u < 4; u++) {
            int pos = row * 40 + 4 * xq + u;
            u32x4 w;
            w[0] = (unsigned)f2bf(fv[0][u]) | ((unsigned)f2bf(fv[1][u]) << 16);
            w[1] = (unsigned)f2bf(fv[2][u]) | ((unsigned)f2bf(fv[3][u]) << 16);
            w[2] = (unsigned)f2bf(fv[4][u]) | ((unsigned)f2bf(fv[5][u]) << 16);
            w[3] = (unsigned)f2bf(fv[6][u]) | ((unsigned)f2bf(fv[7][u]) << 16);
            *(u32x4*)(xs + xs_addr(pos, co * 16)) = w;
        }
    }
    __syncthreads();

    {
        bf16x8 bA[4];
        #pragma unroll
        for (int s = 0; s < 4; s++)
            bA[s] = *(const bf16x8*)(Wg + ((s*2+g)*32 + i31) * 8);
        float biasA = biasb[i31];
        for (int mt = wv; mt < 11; mt += 8) {
            int m0 = mt * 32;
            f32x16 acc = zero16();
            int qr = m0 + i31; if (qr > 339) qr = 339;
            int hy = qr / 34, hx = qr - hy * 34;
            int pos = hy * 40 + hx + 3;
            #pragma unroll
            for (int s = 0; s < 4; s++) {
                bf16x8 a = *(const bf16x8*)(xs + xs_addr(pos, s * 32 + g * 16));
                acc = MFMA32(a, bA[s], acc);
            }
            #pragma unroll
            for (int r = 0; r < 16; r++) {
                int q = m0 + (r & 3) + 8 * (r >> 2) + 4 * g;
                if (q < 340) {
                    int hy2 = q / 34, hx2 = q - hy2 * 34;
                    int gy = y0 - 1 + hy2, gx = x0 - 1 + hx2;
                    bool valid = ((unsigned)gy < 256u) && ((unsigned)gx < 256u);
                    float vv = valid ? (acc[r] + biasA) : 0.f;
                    *(unsigned short*)(t1s + t1_addr(q, i31 * 2)) = f2bf(vv);
                }
            }
        }
    }
    __syncthreads();

    float* outb = out + (size_t)b * (64 * 65536);
    const int y = y0 + wv;

    f32x16 aM = zero16(), aG = zero16(), aX = zero16();
    {
        bf16x8 bg[4], bx[4];
        #pragma unroll
        for (int s = 0; s < 4; s++) {
            bg[s] = *(const bf16x8*)(Wg + 20480 + ((s*2+g)*32 + i31) * 8);
            bx[s] = *(const bf16x8*)(Wg + 22528 + ((s*2+g)*32 + i31) * 8);
        }
        for (int tap = 0; tap < 9; tap++) {
            int dy = tap / 3 - 1, dx = tap - (tap / 3) * 3 - 1;
            int pos = (wv + 1 + dy) * 40 + 4 + dx + i31;
            #pragma unroll
            for (int s = 0; s < 4; s++) {
                bf16x8 bm = *(const bf16x8*)(Wg + 2048 + (((tap*4+s)*2+g)*32 + i31) * 8);
                bf16x8 a = *(const bf16x8*)(xs + xs_addr(pos, s * 32 + g * 16));
                aM = MFMA32(a, bm, aM);
                aG = MFMA32(a, bg[s], aG);
                if (tap == 4) aX = MFMA32(a, bx[s], aX);
            }
        }
    }
    store4(outb, aM, och_g, biasb + 32, 0,  y, x0, i31, g);
    store4(outb, aX, och_g, biasb + 64, 32, y, x0, i31, g);
    store4avg(outb, aG, och_g, biasb, y, x0, i31, g);

    f32x16 aC = zero16();
    for (int tap = 0; tap < 9; tap++) {
        int dy = tap / 3 - 1, dx = tap - (tap / 3) * 3 - 1;
        int q = (wv + 1 + dy) * 34 + 1 + dx + i31;
        #pragma unroll
        for (int s = 0; s < 2; s++) {
            bf16x8 bc = *(const bf16x8*)(Wg + 24576 + (((tap*2+s)*2+g)*32 + i31) * 8);
            bf16x8 a = *(const bf16x8*)(t1s + t1_addr(q, s * 32 + g * 16));
            aC = MFMA32(a, bc, aC);
        }
    }
    store4(outb, aC, och_g, biasb + 96, 64, y, x0, i31, g);
}

// ---------------------------------------------------------------------------
extern "C" void kernel_launch(void* const* d_in, const int* in_sizes, int n_in,
                              void* d_out, int out_size, void* d_ws, size_t ws_size,
                              hipStream_t stream)
{
    const float* x        = (const float*)d_in[0];
    const float* w_main   = (const float*)d_in[1];
    const float* bn_main  = (const float*)d_in[2];
    const float* w_1x1    = (const float*)d_in[3];
    const float* bn_1x1   = (const float*)d_in[4];
    const float* w_3x3_1  = (const float*)d_in[5];
    const float* bn_3x3_1 = (const float*)d_in[6];
    const float* w_3x3_2  = (const float*)d_in[7];
    const float* bn_3x3_2 = (const float*)d_in[8];
    const float* w_avg    = (const float*)d_in[9];
    const float* bn_avg_1 = (const float*)d_in[10];
    const float* bn_avg_2 = (const float*)d_in[11];
    const float* c_score  = (const float*)d_in[12];

    int*   och   = (int*)d_ws;
    float* biasb = (float*)((char*)d_ws + 512);
    __hip_bfloat16* wb = (__hip_bfloat16*)((char*)d_ws + 2048);

    const bool big = (ws_size >= WS_NEED);
    prep_kernel<<<big ? 394 : 4, 256, 0, stream>>>(
        c_score, w_main, bn_main, w_1x1, bn_1x1,
        w_3x3_1, bn_3x3_1, w_3x3_2, bn_3x3_2, w_avg, bn_avg_1, bn_avg_2,
        och, biasb, wb, (unsigned char*)d_ws);

    if (big) {
        unsigned short* xt  = (unsigned short*)((char*)d_ws + XT_OFF);
        unsigned short* t1g = (unsigned short*)((char*)d_ws + T1_OFF);

        t_kernel<<<dim3(2, 256, 8), 256, 0, stream>>>(x, xt);
        m1_kernel<<<dim3(2, 256, 8), 256, 0, stream>>>(xt, wb, biasb, t1g);
        m2ab_kernel<<<dim3(8, 32, 16), 256, 0, stream>>>(
            xt, t1g, wb, och, biasb, (float*)d_out);
    } else {
        fused_fallback<<<dim3(8, 32, 8), 512, 0, stream>>>(
            x, wb, och, biasb, (float*)d_out);
    }
}

// Round 16
// 142.675 us; speedup vs baseline: 1.1392x; 1.0062x over previous
//
#include <hip/hip_runtime.h>
#include <hip/hip_bf16.h>

// ---------------------------------------------------------------------------
// Round 16: r15 (143.6us verified) + three levers:
//   1) m2ab __launch_bounds__(256,3) -> 3 blocks/CU (was 2; LDS+VGPR permit).
//   2) z-parity interleave (even=m2a, odd=m2b) for heterogeneous co-residency.
//   3) pad-zeroing folded into T (xt pads) and M1 (t1g pads); prep = 4 blocks.
// Chain: prep -> T(+xt pads) -> M1(+t1g pads) -> M2AB.
// xt  : chunked  [b][ry 258][c8 8][cx 264][16B]  bf16
// t1g : px-major [b][ry 258][cx 264][32ch]       bf16
// ---------------------------------------------------------------------------

typedef __attribute__((ext_vector_type(8))) short bf16x8;
typedef __attribute__((ext_vector_type(16))) float f32x16;
typedef __attribute__((ext_vector_type(4))) unsigned int u32x4;

#define MFMA32(a,b,c) __builtin_amdgcn_mfma_f32_32x32x16_bf16(a,b,c,0,0,0)

#define XT_OFF   131072ull
#define T1_OFF   69877760ull
#define WS_NEED  104751104ull
#define ROWP     264
#define BROW     258

__device__ __forceinline__ unsigned short f2bf(float f) {
    union { __hip_bfloat16 h; unsigned short u; } cv;
    cv.h = __float2bfloat16(f);
    return cv.u;
}

__device__ __forceinline__ f32x16 zero16() {
    f32x16 z;
    #pragma unroll
    for (int i = 0; i < 16; i++) z[i] = 0.f;
    return z;
}

// fallback LDS addressing (round-3 kernel, verified)
__device__ __forceinline__ int xs_addr(int pos, int byteoff) {
    return pos * 128 + (byteoff ^ (((pos >> 2) & 7) << 4));
}
__device__ __forceinline__ int t1_addr(int pos, int byteoff) {
    return pos * 64 + (byteoff ^ ((pos & 3) << 4));
}

// ---------------------------------------------------------------------------
// prep (4 blocks): weights/biases/och only (pad zeroing moved to T/M1).
// Weight layout (bf16 elements from wb base):
//   wA   @0     [s4][g2][o32][8]        (2048)
//   wM   @2048  [tap9][s4][g2][o32][8]  (18432)
//   wAvg @20480 [s4][g2][o32][8]        (2048)
//   w1x1 @22528 [s4][g2][o32][8]        (2048)
//   wC   @24576 [tap9][s2][g2][o32][8]  (9216)
// ---------------------------------------------------------------------------
__global__ void prep_kernel(
    const float* __restrict__ c_score,
    const float* __restrict__ w_main, const float* __restrict__ bn_main,
    const float* __restrict__ w_1x1,  const float* __restrict__ bn_1x1,
    const float* __restrict__ w_3x3_1,const float* __restrict__ bn_3x3_1,
    const float* __restrict__ w_3x3_2,const float* __restrict__ bn_3x3_2,
    const float* __restrict__ w_avg,  const float* __restrict__ bn_avg_1,
    const float* __restrict__ bn_avg_2,
    int* __restrict__ och, float* __restrict__ biasb,
    __hip_bfloat16* __restrict__ wb)
{
    const int t = threadIdx.x;
    const int bid = blockIdx.x;

    __shared__ float ssc[128];
    __shared__ float iv[6][32];

    if (t < 128) ssc[t] = 1.f / (1.f + expf(-c_score[t]));
    if (t < 32) {
        iv[0][t] = bn_main[t]  * rsqrtf(bn_main[96+t]  + 1e-5f);
        iv[1][t] = bn_1x1[t]   * rsqrtf(bn_1x1[96+t]   + 1e-5f);
        iv[2][t] = bn_3x3_1[t] * rsqrtf(bn_3x3_1[96+t] + 1e-5f);
        iv[3][t] = bn_3x3_2[t] * rsqrtf(bn_3x3_2[96+t] + 1e-5f);
        iv[4][t] = bn_avg_1[t] * rsqrtf(bn_avg_1[96+t] + 1e-5f);
        iv[5][t] = bn_avg_2[t] * rsqrtf(bn_avg_2[96+t] + 1e-5f);
    }
    __syncthreads();

    if (bid == 0) {
        if (t < 128) {
            float sj = c_score[t];
            int r = 0;
            for (int i = 0; i < 128; i++) {
                float si = c_score[i];
                r += (si > sj) || (si == sj && i < t);
            }
            och[t] = (r < 64) ? r : -1;
        }
        if (t < 32) {
            biasb[t]     = bn_3x3_1[32+t] - bn_3x3_1[64+t]*iv[2][t];
            biasb[32+t]  = (bn_main[32+t]  - bn_main[64+t]*iv[0][t])  * ssc[t];
            biasb[64+t]  = (bn_1x1[32+t]   - bn_1x1[64+t]*iv[1][t])   * ssc[32+t];
            biasb[96+t]  = (bn_3x3_2[32+t] - bn_3x3_2[64+t]*iv[3][t]) * ssc[64+t];
            biasb[128+t] = (bn_avg_2[32+t] - bn_avg_2[64+t]*iv[5][t]) * ssc[96+t];
            float b1p = bn_avg_1[32+t] - bn_avg_1[64+t]*iv[4][t];
            biasb[160+t] = ssc[96+t] * iv[5][t] * b1p * (1.f/9.f);
        }
    } else if (bid == 1) {
        for (int i = t; i < 2048; i += 256) {
            int j = i & 7, o = (i >> 3) & 31, g = (i >> 8) & 1, s = i >> 9;
            int c = s * 16 + g * 8 + j;
            wb[i]         = __float2bfloat16(w_3x3_1[o*64+c] * iv[2][o]);
            wb[20480 + i] = __float2bfloat16(w_avg[o*64+c] * iv[4][o] * iv[5][o] * (1.f/9.f) * ssc[96+o]);
            wb[22528 + i] = __float2bfloat16(w_1x1[o*64+c] * iv[1][o] * ssc[32+o]);
        }
    } else if (bid == 2) {
        for (int i = t; i < 18432; i += 256) {
            int j = i & 7, o = (i >> 3) & 31, g = (i >> 8) & 1;
            int s = (i >> 9) & 3, tap = i >> 11;
            int c = s * 16 + g * 8 + j;
            wb[2048 + i] = __float2bfloat16(w_main[o*576 + c*9 + tap] * iv[0][o] * ssc[o]);
        }
    } else {
        for (int i = t; i < 9216; i += 256) {
            int j = i & 7, o = (i >> 3) & 31, g = (i >> 8) & 1;
            int s = (i >> 9) & 1, tap = i >> 10;
            int c = s * 16 + g * 8 + j;
            wb[24576 + i] = __float2bfloat16(w_3x3_2[o*288 + c*9 + tap] * iv[3][o] * ssc[64+o]);
        }
    }
}

// ---------------------------------------------------------------------------
// T: pure transpose x NCHW fp32 -> xt chunked bf16, + zero xt pad cells.
// grid (2, 256, 8), 256 thr.  No LDS, no barrier.
// ---------------------------------------------------------------------------
__global__ __launch_bounds__(256, 8) void t_kernel(
    const float* __restrict__ x, unsigned short* __restrict__ xt)
{
    const int t = threadIdx.x;
    const int co = t >> 5, pq = t & 31;
    const int y = blockIdx.y, b = blockIdx.z;
    const int pxa = blockIdx.x * 128 + pq * 4;

    const float* xp = x + ((size_t)(b * 64 + co * 8) * 65536) + y * 256 + pxa;
    float4 f[8];
    #pragma unroll
    for (int k = 0; k < 8; k++)
        f[k] = *(const float4*)(xp + (size_t)k * 65536);

    size_t xrow = ((size_t)(b * BROW + y + 1) * 8 + co) * ROWP;   // chunk units
    #pragma unroll
    for (int u = 0; u < 4; u++) {
        u32x4 w;
        #pragma unroll
        for (int j = 0; j < 4; j++) {
            const float* a  = (const float*)&f[2*j];
            const float* c2 = (const float*)&f[2*j+1];
            w[j] = (unsigned)f2bf(a[u]) | ((unsigned)f2bf(c2[u]) << 16);
        }
        *(u32x4*)(xt + (xrow + pxa + u + 1) * 8) = w;
    }

    // ---- xt pad zeroing (replaces the old Z dispatch) ----
    if (blockIdx.x == 0) {
        u32x4 z = {0, 0, 0, 0};
        if (t < 16) {        // side pads for this row (ry = y+1): cx = 0, 257
            int c = t & 7, side = t >> 3;
            size_t ch = ((size_t)(b * BROW + y + 1) * 8 + c) * ROWP + (side ? 257 : 0);
            *(u32x4*)(xt + ch * 8) = z;
        }
        if (y < 2) {         // full pad rows ry = 0 (y==0) and ry = 257 (y==1)
            int ry = (y == 0) ? 0 : 257;
            for (int j = t; j < 2112; j += 256) {
                int c = j / 264, cx = j - c * 264;
                size_t ch = ((size_t)(b * BROW + ry) * 8 + c) * ROWP + cx;
                *(u32x4*)(xt + ch * 8) = z;
            }
        }
    }
}

// ---------------------------------------------------------------------------
// M1: t1 = BN(1x1 conv) from xt via direct global fragment loads,
// + zero t1g pad cells.  grid (2,256,8), 256 thr.
// ---------------------------------------------------------------------------
__global__ __launch_bounds__(256, 8) void m1_kernel(
    const unsigned short* __restrict__ xt,
    const __hip_bfloat16* __restrict__ Wg,
    const float* __restrict__ biasb,
    unsigned short* __restrict__ t1g)
{
    const int t = threadIdx.x;
    const int lane = t & 63, wv = t >> 6;
    const int i31 = lane & 31, g = lane >> 5;
    const int y = blockIdx.y, b = blockIdx.z;
    const int px0 = blockIdx.x * 128, m0 = wv * 32;

    size_t rowb = (size_t)(b * BROW + y + 1) * 8;   // chunk-row base
    f32x16 acc = zero16();
    #pragma unroll
    for (int s = 0; s < 4; s++) {
        int ch = s * 2 + g;
        bf16x8 a  = *(const bf16x8*)(xt + ((rowb + ch) * ROWP + px0 + m0 + i31 + 1) * 8);
        bf16x8 bA = *(const bf16x8*)(Wg + (ch * 32 + i31) * 8);
        acc = MFMA32(a, bA, acc);
    }
    float bias = biasb[i31];
    size_t trow = (size_t)(b * BROW + y + 1) * ROWP;
    #pragma unroll
    for (int r = 0; r < 16; r++) {
        int px = m0 + (r & 3) + 8 * (r >> 2) + 4 * g;
        t1g[(trow + px0 + px + 1) * 32 + i31] = f2bf(acc[r] + bias);   // 2x64B/instr
    }

    // ---- t1g pad zeroing ----
    if (blockIdx.x == 0) {
        u32x4 z = {0, 0, 0, 0};
        if (t < 8) {         // side pads for this row: cx = 0, 257 (4 chunks each)
            int c4 = t & 3, side = t >> 2;
            size_t px = (size_t)(b * BROW + y + 1) * ROWP + (side ? 257 : 0);
            *(u32x4*)(t1g + px * 32 + c4 * 8) = z;
        }
        if (y < 2) {         // full pad rows ry = 0 / 257
            int ry = (y == 0) ? 0 : 257;
            for (int j = t; j < 1056; j += 256) {
                int pxi = j >> 2, c4 = j & 3;
                size_t px = (size_t)(b * BROW + ry) * ROWP + pxi;
                *(u32x4*)(t1g + px * 32 + c4 * 8) = z;
            }
        }
    }
}

// ---------------------------------------------------------------------------
// store helpers (verified r9 epilogue; lane = och layout)
// ---------------------------------------------------------------------------
__device__ __forceinline__ void store4(float* outb, const f32x16& acc,
    const int* __restrict__ och_g, const float* __restrict__ bias32,
    int cbase, int y, int x0, int i31, int g)
{
    int rank = och_g[cbase + i31];
    if (rank < 0) return;
    float bias = bias32[i31];
    float* po = outb + (size_t)rank * 65536 + y*256 + x0 + 4*g;
    #pragma unroll
    for (int q = 0; q < 4; q++) {
        float4 v;
        v.x = acc[4*q+0] + bias;
        v.y = acc[4*q+1] + bias;
        v.z = acc[4*q+2] + bias;
        v.w = acc[4*q+3] + bias;
        *(float4*)(po + 8*q) = v;
    }
}

__device__ __forceinline__ void store4avg(float* outb, const f32x16& acc,
    const int* __restrict__ och_g, const float* __restrict__ biasb,
    int y, int x0, int i31, int g)
{
    int rank = och_g[96 + i31];
    if (rank < 0) return;
    float t2b = biasb[128 + i31];
    float b19 = biasb[160 + i31];
    float cy = 3.f - (float)(y == 0) - (float)(y == 255);
    float* po = outb + (size_t)rank * 65536 + y*256 + x0 + 4*g;
    #pragma unroll
    for (int q = 0; q < 4; q++) {
        float4 v;
        #pragma unroll
        for (int u = 0; u < 4; u++) {
            int gx = x0 + 4*g + 8*q + u;
            float cx = 3.f - (float)(gx == 0) - (float)(gx == 255);
            ((float*)&v)[u] = acc[4*q+u] + t2b + b19 * (cy * cx);
        }
        *(float4*)(po + 8*q) = v;
    }
}

// ---------------------------------------------------------------------------
// M2AB: one dispatch, two block paths, z-parity interleaved:
//   z even : m2a path, b = z>>1   (LDS 43520 B, [c8][10][34])
//   z odd  : m2b path, b = z>>1   (LDS 22400 B, [c4][10][35] padded)
// grid (8,32,16), 256 thr / 4 waves; wave -> 2 output rows; 3 blocks/CU.
// ---------------------------------------------------------------------------
__global__ __launch_bounds__(256, 3) void m2ab_kernel(
    const unsigned short* __restrict__ xt,
    const unsigned short* __restrict__ t1g,
    const __hip_bfloat16* __restrict__ Wg,
    const int* __restrict__ och_g,
    const float* __restrict__ biasb,
    float* __restrict__ out)
{
    __shared__ __align__(16) unsigned char smem[43520];

    const int t = threadIdx.x;
    const int lane = t & 63, wv = t >> 6;
    const int i31 = lane & 31, g = lane >> 5;
    const int x0 = blockIdx.x * 32, y0 = blockIdx.y * 8;
    const int zz = blockIdx.z;
    const int b = zz >> 1;

    const int y_0 = y0 + 2 * wv, y_1 = y_0 + 1;      // output rows
    const int r0 = 2 * wv + 1, r1 = r0 + 1;          // halo rows

    if ((zz & 1) == 0) {
        // ================= m2a path =================
        unsigned short* xs = (unsigned short*)smem;   // [c8][10][34] chunks
        {
            u32x4 tmp[11];
            int   jj[11];
            #pragma unroll
            for (int i = 0; i < 11; i++) {
                int j = t + i * 256;
                if (j > 2719) j = 2719;
                jj[i] = j;
                int c = j / 340, rem = j - c * 340, r = rem / 34, p = rem - r * 34;
                size_t src = ((size_t)(b * BROW + y0 + r) * 8 + c) * ROWP + x0 + p;
                tmp[i] = *(const u32x4*)(xt + src * 8);
            }
            #pragma unroll
            for (int i = 0; i < 11; i++)
                *(u32x4*)(xs + (size_t)jj[i] * 8) = tmp[i];
        }
        __syncthreads();

        float* outb = out + (size_t)b * (64 * 65536);
        f32x16 aM0 = zero16(), aM1 = zero16();
        f32x16 aG0 = zero16(), aG1 = zero16();
        f32x16 aX0 = zero16(), aX1 = zero16();
        {
            bf16x8 bg[4], bx[4];
            #pragma unroll
            for (int s = 0; s < 4; s++) {
                bg[s] = *(const bf16x8*)(Wg + 20480 + ((s*2+g)*32 + i31) * 8);
                bx[s] = *(const bf16x8*)(Wg + 22528 + ((s*2+g)*32 + i31) * 8);
            }
            #pragma unroll
            for (int tap = 0; tap < 9; tap++) {
                int dy = tap / 3 - 1, dx = tap - (tap / 3) * 3 - 1;
                int pbase = i31 + dx + 1;
                #pragma unroll
                for (int s = 0; s < 4; s++) {
                    bf16x8 bm = *(const bf16x8*)(Wg + 2048 + (((tap*4+s)*2+g)*32 + i31) * 8);
                    bf16x8 a0 = *(const bf16x8*)(xs + (size_t)(((s*2+g) * 10 + r0 + dy) * 34 + pbase) * 8);
                    bf16x8 a1 = *(const bf16x8*)(xs + (size_t)(((s*2+g) * 10 + r1 + dy) * 34 + pbase) * 8);
                    aM0 = MFMA32(a0, bm, aM0);
                    aM1 = MFMA32(a1, bm, aM1);
                    aG0 = MFMA32(a0, bg[s], aG0);
                    aG1 = MFMA32(a1, bg[s], aG1);
                    if (tap == 4) {
                        aX0 = MFMA32(a0, bx[s], aX0);
                        aX1 = MFMA32(a1, bx[s], aX1);
                    }
                }
            }
        }
        store4(outb, aM0, och_g, biasb + 32, 0,  y_0, x0, i31, g);  // main -> [0,32)
        store4(outb, aM1, och_g, biasb + 32, 0,  y_1, x0, i31, g);
        store4(outb, aX0, och_g, biasb + 64, 32, y_0, x0, i31, g);  // 1x1  -> [32,64)
        store4(outb, aX1, och_g, biasb + 64, 32, y_1, x0, i31, g);
        store4avg(outb, aG0, och_g, biasb, y_0, x0, i31, g);        // avg  -> [96,128)
        store4avg(outb, aG1, och_g, biasb, y_1, x0, i31, g);
    } else {
        // ================= m2b path =================
        unsigned short* t1s = (unsigned short*)smem;  // [c4][10][35] chunks (padded)
        #pragma unroll
        for (int i = 0; i < 6; i++) {
            int j = t + i * 256;
            if (j > 1359) j = 1359;
            int c4 = j & 3, pr = j >> 2;
            int r = pr / 34, p = pr - r * 34;
            size_t src = ((size_t)(b * BROW + y0 + r) * ROWP + x0 + p) * 32 + c4 * 8;
            int ci = c4 * 350 + r * 35 + p;
            *(u32x4*)(t1s + (size_t)ci * 8) = *(const u32x4*)(t1g + src);
        }
        __syncthreads();

        float* outb = out + (size_t)b * (64 * 65536);
        f32x16 aC0 = zero16(), aC1 = zero16();
        #pragma unroll
        for (int tap = 0; tap < 9; tap++) {
            int dy = tap / 3 - 1, dx = tap - (tap / 3) * 3 - 1;
            int pbase = i31 + dx + 1;
            #pragma unroll
            for (int s = 0; s < 2; s++) {
                bf16x8 bc = *(const bf16x8*)(Wg + 24576 + (((tap*2+s)*2+g)*32 + i31) * 8);
                bf16x8 a0 = *(const bf16x8*)(t1s + (size_t)((s*2+g) * 350 + (r0 + dy) * 35 + pbase) * 8);
                bf16x8 a1 = *(const bf16x8*)(t1s + (size_t)((s*2+g) * 350 + (r1 + dy) * 35 + pbase) * 8);
                aC0 = MFMA32(a0, bc, aC0);
                aC1 = MFMA32(a1, bc, aC1);
            }
        }
        store4(outb, aC0, och_g, biasb + 96, 64, y_0, x0, i31, g);  // 3x3 -> [64,96)
        store4(outb, aC1, och_g, biasb + 96, 64, y_1, x0, i31, g);
    }
}

// ---------------------------------------------------------------------------
// Fallback: round-3 single fused kernel (r8 weight addressing) for small ws.
// ---------------------------------------------------------------------------
__global__ __launch_bounds__(512, 4) void fused_fallback(
    const float* __restrict__ x,
    const __hip_bfloat16* __restrict__ Wg,
    const int* __restrict__ och_g,
    const float* __restrict__ biasb,
    float* __restrict__ out)
{
    __shared__ __align__(16) unsigned char xs[400 * 128];
    __shared__ __align__(16) unsigned char t1s[340 * 64];

    const int t = threadIdx.x;
    const int lane = t & 63, wv = t >> 6;
    const int i31 = lane & 31, g = lane >> 5;
    const int x0 = blockIdx.x * 32, y0 = blockIdx.y * 8;
    const int b = blockIdx.z;

    const float* xb = x + (size_t)b * (64 * 65536);
    for (int j = t; j < 800; j += 512) {
        int co = j / 100;
        int rem = j - co * 100;
        int row = rem / 10, xq = rem - row * 10;
        int gy = y0 - 1 + row;
        int gx0 = x0 - 4 + 4 * xq;
        bool ok = ((unsigned)gy < 256u) && ((unsigned)gx0 <= 252u);
        const float* p = xb + (size_t)(co * 8) * 65536 + (size_t)gy * 256 + gx0;
        float4 f0 = {0,0,0,0}, f1 = {0,0,0,0}, f2 = {0,0,0,0}, f3 = {0,0,0,0};
        float4 f4 = {0,0,0,0}, f5 = {0,0,0,0}, f6 = {0,0,0,0}, f7 = {0,0,0,0};
        if (ok) {
            f0 = *(const float4*)(p);
            f1 = *(const float4*)(p + 65536);
            f2 = *(const float4*)(p + 131072);
            f3 = *(const float4*)(p + 196608);
            f4 = *(const float4*)(p + 262144);
            f5 = *(const float4*)(p + 327680);
            f6 = *(const float4*)(p + 393216);
            f7 = *(const float4*)(p + 458752);
        }
        const float* fv[8] = {(const float*)&f0, (const float*)&f1, (const float*)&f2,
                              (const float*)&f3, (const float*)&f4, (const float*)&f5,
                              (const float*)&f6, (const float*)&f7};
        #pragma unroll
        for (int u = 0; u < 4; u++) {
            int pos = row * 40 + 4 * xq + u;
            u32x4 w;
            w[0] = (unsigned)f2bf(fv[0][u]) | ((unsigned)f2bf(fv[1][u]) << 16);
            w[1] = (unsigned)f2bf(fv[2][u]) | ((unsigned)f2bf(fv[3][u]) << 16);
            w[2] = (unsigned)f2bf(fv[4][u]) | ((unsigned)f2bf(fv[5][u]) << 16);
            w[3] = (unsigned)f2bf(fv[6][u]) | ((unsigned)f2bf(fv[7][u]) << 16);
            *(u32x4*)(xs + xs_addr(pos, co * 16)) = w;
        }
    }
    __syncthreads();

    {
        bf16x8 bA[4];
        #pragma unroll
        for (int s = 0; s < 4; s++)
            bA[s] = *(const bf16x8*)(Wg + ((s*2+g)*32 + i31) * 8);
        float biasA = biasb[i31];
        for (int mt = wv; mt < 11; mt += 8) {
            int m0 = mt * 32;
            f32x16 acc = zero16();
            int qr = m0 + i31; if (qr > 339) qr = 339;
            int hy = qr / 34, hx = qr - hy * 34;
            int pos = hy * 40 + hx + 3;
            #pragma unroll
            for (int s = 0; s < 4; s++) {
                bf16x8 a = *(const bf16x8*)(xs + xs_addr(pos, s * 32 + g * 16));
                acc = MFMA32(a, bA[s], acc);
            }
            #pragma unroll
            for (int r = 0; r < 16; r++) {
                int q = m0 + (r & 3) + 8 * (r >> 2) + 4 * g;
                if (q < 340) {
                    int hy2 = q / 34, hx2 = q - hy2 * 34;
                    int gy = y0 - 1 + hy2, gx = x0 - 1 + hx2;
                    bool valid = ((unsigned)gy < 256u) && ((unsigned)gx < 256u);
                    float vv = valid ? (acc[r] + biasA) : 0.f;
                    *(unsigned short*)(t1s + t1_addr(q, i31 * 2)) = f2bf(vv);
                }
            }
        }
    }
    __syncthreads();

    float* outb = out + (size_t)b * (64 * 65536);
    const int y = y0 + wv;

    f32x16 aM = zero16(), aG = zero16(), aX = zero16();
    {
        bf16x8 bg[4], bx[4];
        #pragma unroll
        for (int s = 0; s < 4; s++) {
            bg[s] = *(const bf16x8*)(Wg + 20480 + ((s*2+g)*32 + i31) * 8);
            bx[s] = *(const bf16x8*)(Wg + 22528 + ((s*2+g)*32 + i31) * 8);
        }
        for (int tap = 0; tap < 9; tap++) {
            int dy = tap / 3 - 1, dx = tap - (tap / 3) * 3 - 1;
            int pos = (wv + 1 + dy) * 40 + 4 + dx + i31;
            #pragma unroll
            for (int s = 0; s < 4; s++) {
                bf16x8 bm = *(const bf16x8*)(Wg + 2048 + (((tap*4+s)*2+g)*32 + i31) * 8);
                bf16x8 a = *(const bf16x8*)(xs + xs_addr(pos, s * 32 + g * 16));
                aM = MFMA32(a, bm, aM);
                aG = MFMA32(a, bg[s], aG);
                if (tap == 4) aX = MFMA32(a, bx[s], aX);
            }
        }
    }
    store4(outb, aM, och_g, biasb + 32, 0,  y, x0, i31, g);
    store4(outb, aX, och_g, biasb + 64, 32, y, x0, i31, g);
    store4avg(outb, aG, och_g, biasb, y, x0, i31, g);

    f32x16 aC = zero16();
    for (int tap = 0; tap < 9; tap++) {
        int dy = tap / 3 - 1, dx = tap - (tap / 3) * 3 - 1;
        int q = (wv + 1 + dy) * 34 + 1 + dx + i31;
        #pragma unroll
        for (int s = 0; s < 2; s++) {
            bf16x8 bc = *(const bf16x8*)(Wg + 24576 + (((tap*2+s)*2+g)*32 + i31) * 8);
            bf16x8 a = *(const bf16x8*)(t1s + t1_addr(q, s * 32 + g * 16));
            aC = MFMA32(a, bc, aC);
        }
    }
    store4(outb, aC, och_g, biasb + 96, 64, y, x0, i31, g);
}

// ---------------------------------------------------------------------------
extern "C" void kernel_launch(void* const* d_in, const int* in_sizes, int n_in,
                              void* d_out, int out_size, void* d_ws, size_t ws_size,
                              hipStream_t stream)
{
    const float* x        = (const float*)d_in[0];
    const float* w_main   = (const float*)d_in[1];
    const float* bn_main  = (const float*)d_in[2];
    const float* w_1x1    = (const float*)d_in[3];
    const float* bn_1x1   = (const float*)d_in[4];
    const float* w_3x3_1  = (const float*)d_in[5];
    const float* bn_3x3_1 = (const float*)d_in[6];
    const float* w_3x3_2  = (const float*)d_in[7];
    const float* bn_3x3_2 = (const float*)d_in[8];
    const float* w_avg    = (const float*)d_in[9];
    const float* bn_avg_1 = (const float*)d_in[10];
    const float* bn_avg_2 = (const float*)d_in[11];
    const float* c_score  = (const float*)d_in[12];

    int*   och   = (int*)d_ws;
    float* biasb = (float*)((char*)d_ws + 512);
    __hip_bfloat16* wb = (__hip_bfloat16*)((char*)d_ws + 2048);

    prep_kernel<<<4, 256, 0, stream>>>(
        c_score, w_main, bn_main, w_1x1, bn_1x1,
        w_3x3_1, bn_3x3_1, w_3x3_2, bn_3x3_2, w_avg, bn_avg_1, bn_avg_2,
        och, biasb, wb);

    if (ws_size >= WS_NEED) {
        unsigned short* xt  = (unsigned short*)((char*)d_ws + XT_OFF);
        unsigned short* t1g = (unsigned short*)((char*)d_ws + T1_OFF);

        t_kernel<<<dim3(2, 256, 8), 256, 0, stream>>>(x, xt);
        m1_kernel<<<dim3(2, 256, 8), 256, 0, stream>>>(xt, wb, biasb, t1g);
        m2ab_kernel<<<dim3(8, 32, 16), 256, 0, stream>>>(
            xt, t1g, wb, och, biasb, (float*)d_out);
    } else {
        fused_fallback<<<dim3(8, 32, 8), 512, 0, stream>>>(
            x, wb, och, biasb, (float*)d_out);
    }
}

// Round 17
// 141.282 us; speedup vs baseline: 1.1505x; 1.0099x over previous
//
#include <hip/hip_runtime.h>
#include <hip/hip_bf16.h>

// ---------------------------------------------------------------------------
// Round 17: r16 (142.7us verified) + register-pressure fix in m2ab's m2a path:
// the 1x1 branch is computed and stored FIRST (phase 1, 2 accs), then the
// main+avg tap loop runs with only 4 live accumulators (was 6 -> 96 AGPR,
// capping occupancy at 2 blocks/CU; now ~148 regs -> 3 blocks/CU).
// Chain: prep -> T(+xt pads) -> M1(+t1g pads) -> M2AB.
// xt  : chunked  [b][ry 258][c8 8][cx 264][16B]  bf16
// t1g : px-major [b][ry 258][cx 264][32ch]       bf16
// ---------------------------------------------------------------------------

typedef __attribute__((ext_vector_type(8))) short bf16x8;
typedef __attribute__((ext_vector_type(16))) float f32x16;
typedef __attribute__((ext_vector_type(4))) unsigned int u32x4;

#define MFMA32(a,b,c) __builtin_amdgcn_mfma_f32_32x32x16_bf16(a,b,c,0,0,0)

#define XT_OFF   131072ull
#define T1_OFF   69877760ull
#define WS_NEED  104751104ull
#define ROWP     264
#define BROW     258

__device__ __forceinline__ unsigned short f2bf(float f) {
    union { __hip_bfloat16 h; unsigned short u; } cv;
    cv.h = __float2bfloat16(f);
    return cv.u;
}

__device__ __forceinline__ f32x16 zero16() {
    f32x16 z;
    #pragma unroll
    for (int i = 0; i < 16; i++) z[i] = 0.f;
    return z;
}

// fallback LDS addressing (round-3 kernel, verified)
__device__ __forceinline__ int xs_addr(int pos, int byteoff) {
    return pos * 128 + (byteoff ^ (((pos >> 2) & 7) << 4));
}
__device__ __forceinline__ int t1_addr(int pos, int byteoff) {
    return pos * 64 + (byteoff ^ ((pos & 3) << 4));
}

// ---------------------------------------------------------------------------
// prep (4 blocks): weights/biases/och.
// Weight layout (bf16 elements from wb base):
//   wA   @0     [s4][g2][o32][8]        (2048)
//   wM   @2048  [tap9][s4][g2][o32][8]  (18432)
//   wAvg @20480 [s4][g2][o32][8]        (2048)
//   w1x1 @22528 [s4][g2][o32][8]        (2048)
//   wC   @24576 [tap9][s2][g2][o32][8]  (9216)
// ---------------------------------------------------------------------------
__global__ void prep_kernel(
    const float* __restrict__ c_score,
    const float* __restrict__ w_main, const float* __restrict__ bn_main,
    const float* __restrict__ w_1x1,  const float* __restrict__ bn_1x1,
    const float* __restrict__ w_3x3_1,const float* __restrict__ bn_3x3_1,
    const float* __restrict__ w_3x3_2,const float* __restrict__ bn_3x3_2,
    const float* __restrict__ w_avg,  const float* __restrict__ bn_avg_1,
    const float* __restrict__ bn_avg_2,
    int* __restrict__ och, float* __restrict__ biasb,
    __hip_bfloat16* __restrict__ wb)
{
    const int t = threadIdx.x;
    const int bid = blockIdx.x;

    __shared__ float ssc[128];
    __shared__ float iv[6][32];

    if (t < 128) ssc[t] = 1.f / (1.f + expf(-c_score[t]));
    if (t < 32) {
        iv[0][t] = bn_main[t]  * rsqrtf(bn_main[96+t]  + 1e-5f);
        iv[1][t] = bn_1x1[t]   * rsqrtf(bn_1x1[96+t]   + 1e-5f);
        iv[2][t] = bn_3x3_1[t] * rsqrtf(bn_3x3_1[96+t] + 1e-5f);
        iv[3][t] = bn_3x3_2[t] * rsqrtf(bn_3x3_2[96+t] + 1e-5f);
        iv[4][t] = bn_avg_1[t] * rsqrtf(bn_avg_1[96+t] + 1e-5f);
        iv[5][t] = bn_avg_2[t] * rsqrtf(bn_avg_2[96+t] + 1e-5f);
    }
    __syncthreads();

    if (bid == 0) {
        if (t < 128) {
            float sj = c_score[t];
            int r = 0;
            for (int i = 0; i < 128; i++) {
                float si = c_score[i];
                r += (si > sj) || (si == sj && i < t);
            }
            och[t] = (r < 64) ? r : -1;
        }
        if (t < 32) {
            biasb[t]     = bn_3x3_1[32+t] - bn_3x3_1[64+t]*iv[2][t];
            biasb[32+t]  = (bn_main[32+t]  - bn_main[64+t]*iv[0][t])  * ssc[t];
            biasb[64+t]  = (bn_1x1[32+t]   - bn_1x1[64+t]*iv[1][t])   * ssc[32+t];
            biasb[96+t]  = (bn_3x3_2[32+t] - bn_3x3_2[64+t]*iv[3][t]) * ssc[64+t];
            biasb[128+t] = (bn_avg_2[32+t] - bn_avg_2[64+t]*iv[5][t]) * ssc[96+t];
            float b1p = bn_avg_1[32+t] - bn_avg_1[64+t]*iv[4][t];
            biasb[160+t] = ssc[96+t] * iv[5][t] * b1p * (1.f/9.f);
        }
    } else if (bid == 1) {
        for (int i = t; i < 2048; i += 256) {
            int j = i & 7, o = (i >> 3) & 31, g = (i >> 8) & 1, s = i >> 9;
            int c = s * 16 + g * 8 + j;
            wb[i]         = __float2bfloat16(w_3x3_1[o*64+c] * iv[2][o]);
            wb[20480 + i] = __float2bfloat16(w_avg[o*64+c] * iv[4][o] * iv[5][o] * (1.f/9.f) * ssc[96+o]);
            wb[22528 + i] = __float2bfloat16(w_1x1[o*64+c] * iv[1][o] * ssc[32+o]);
        }
    } else if (bid == 2) {
        for (int i = t; i < 18432; i += 256) {
            int j = i & 7, o = (i >> 3) & 31, g = (i >> 8) & 1;
            int s = (i >> 9) & 3, tap = i >> 11;
            int c = s * 16 + g * 8 + j;
            wb[2048 + i] = __float2bfloat16(w_main[o*576 + c*9 + tap] * iv[0][o] * ssc[o]);
        }
    } else {
        for (int i = t; i < 9216; i += 256) {
            int j = i & 7, o = (i >> 3) & 31, g = (i >> 8) & 1;
            int s = (i >> 9) & 1, tap = i >> 10;
            int c = s * 16 + g * 8 + j;
            wb[24576 + i] = __float2bfloat16(w_3x3_2[o*288 + c*9 + tap] * iv[3][o] * ssc[64+o]);
        }
    }
}

// ---------------------------------------------------------------------------
// T: pure transpose x NCHW fp32 -> xt chunked bf16, + zero xt pad cells.
// ---------------------------------------------------------------------------
__global__ __launch_bounds__(256, 8) void t_kernel(
    const float* __restrict__ x, unsigned short* __restrict__ xt)
{
    const int t = threadIdx.x;
    const int co = t >> 5, pq = t & 31;
    const int y = blockIdx.y, b = blockIdx.z;
    const int pxa = blockIdx.x * 128 + pq * 4;

    const float* xp = x + ((size_t)(b * 64 + co * 8) * 65536) + y * 256 + pxa;
    float4 f[8];
    #pragma unroll
    for (int k = 0; k < 8; k++)
        f[k] = *(const float4*)(xp + (size_t)k * 65536);

    size_t xrow = ((size_t)(b * BROW + y + 1) * 8 + co) * ROWP;   // chunk units
    #pragma unroll
    for (int u = 0; u < 4; u++) {
        u32x4 w;
        #pragma unroll
        for (int j = 0; j < 4; j++) {
            const float* a  = (const float*)&f[2*j];
            const float* c2 = (const float*)&f[2*j+1];
            w[j] = (unsigned)f2bf(a[u]) | ((unsigned)f2bf(c2[u]) << 16);
        }
        *(u32x4*)(xt + (xrow + pxa + u + 1) * 8) = w;
    }

    // ---- xt pad zeroing ----
    if (blockIdx.x == 0) {
        u32x4 z = {0, 0, 0, 0};
        if (t < 16) {        // side pads for this row (ry = y+1): cx = 0, 257
            int c = t & 7, side = t >> 3;
            size_t ch = ((size_t)(b * BROW + y + 1) * 8 + c) * ROWP + (side ? 257 : 0);
            *(u32x4*)(xt + ch * 8) = z;
        }
        if (y < 2) {         // full pad rows ry = 0 (y==0) and ry = 257 (y==1)
            int ry = (y == 0) ? 0 : 257;
            for (int j = t; j < 2112; j += 256) {
                int c = j / 264, cx = j - c * 264;
                size_t ch = ((size_t)(b * BROW + ry) * 8 + c) * ROWP + cx;
                *(u32x4*)(xt + ch * 8) = z;
            }
        }
    }
}

// ---------------------------------------------------------------------------
// M1: t1 = BN(1x1 conv) from xt via direct global fragment loads,
// + zero t1g pad cells.
// ---------------------------------------------------------------------------
__global__ __launch_bounds__(256, 8) void m1_kernel(
    const unsigned short* __restrict__ xt,
    const __hip_bfloat16* __restrict__ Wg,
    const float* __restrict__ biasb,
    unsigned short* __restrict__ t1g)
{
    const int t = threadIdx.x;
    const int lane = t & 63, wv = t >> 6;
    const int i31 = lane & 31, g = lane >> 5;
    const int y = blockIdx.y, b = blockIdx.z;
    const int px0 = blockIdx.x * 128, m0 = wv * 32;

    size_t rowb = (size_t)(b * BROW + y + 1) * 8;   // chunk-row base
    f32x16 acc = zero16();
    #pragma unroll
    for (int s = 0; s < 4; s++) {
        int ch = s * 2 + g;
        bf16x8 a  = *(const bf16x8*)(xt + ((rowb + ch) * ROWP + px0 + m0 + i31 + 1) * 8);
        bf16x8 bA = *(const bf16x8*)(Wg + (ch * 32 + i31) * 8);
        acc = MFMA32(a, bA, acc);
    }
    float bias = biasb[i31];
    size_t trow = (size_t)(b * BROW + y + 1) * ROWP;
    #pragma unroll
    for (int r = 0; r < 16; r++) {
        int px = m0 + (r & 3) + 8 * (r >> 2) + 4 * g;
        t1g[(trow + px0 + px + 1) * 32 + i31] = f2bf(acc[r] + bias);   // 2x64B/instr
    }

    // ---- t1g pad zeroing ----
    if (blockIdx.x == 0) {
        u32x4 z = {0, 0, 0, 0};
        if (t < 8) {         // side pads for this row: cx = 0, 257
            int c4 = t & 3, side = t >> 2;
            size_t px = (size_t)(b * BROW + y + 1) * ROWP + (side ? 257 : 0);
            *(u32x4*)(t1g + px * 32 + c4 * 8) = z;
        }
        if (y < 2) {         // full pad rows ry = 0 / 257
            int ry = (y == 0) ? 0 : 257;
            for (int j = t; j < 1056; j += 256) {
                int pxi = j >> 2, c4 = j & 3;
                size_t px = (size_t)(b * BROW + ry) * ROWP + pxi;
                *(u32x4*)(t1g + px * 32 + c4 * 8) = z;
            }
        }
    }
}

// ---------------------------------------------------------------------------
// store helpers (verified r9 epilogue; lane = och layout)
// ---------------------------------------------------------------------------
__device__ __forceinline__ void store4(float* outb, const f32x16& acc,
    const int* __restrict__ och_g, const float* __restrict__ bias32,
    int cbase, int y, int x0, int i31, int g)
{
    int rank = och_g[cbase + i31];
    if (rank < 0) return;
    float bias = bias32[i31];
    float* po = outb + (size_t)rank * 65536 + y*256 + x0 + 4*g;
    #pragma unroll
    for (int q = 0; q < 4; q++) {
        float4 v;
        v.x = acc[4*q+0] + bias;
        v.y = acc[4*q+1] + bias;
        v.z = acc[4*q+2] + bias;
        v.w = acc[4*q+3] + bias;
        *(float4*)(po + 8*q) = v;
    }
}

__device__ __forceinline__ void store4avg(float* outb, const f32x16& acc,
    const int* __restrict__ och_g, const float* __restrict__ biasb,
    int y, int x0, int i31, int g)
{
    int rank = och_g[96 + i31];
    if (rank < 0) return;
    float t2b = biasb[128 + i31];
    float b19 = biasb[160 + i31];
    float cy = 3.f - (float)(y == 0) - (float)(y == 255);
    float* po = outb + (size_t)rank * 65536 + y*256 + x0 + 4*g;
    #pragma unroll
    for (int q = 0; q < 4; q++) {
        float4 v;
        #pragma unroll
        for (int u = 0; u < 4; u++) {
            int gx = x0 + 4*g + 8*q + u;
            float cx = 3.f - (float)(gx == 0) - (float)(gx == 255);
            ((float*)&v)[u] = acc[4*q+u] + t2b + b19 * (cy * cx);
        }
        *(float4*)(po + 8*q) = v;
    }
}

// ---------------------------------------------------------------------------
// M2AB: one dispatch, two block paths, z-parity interleaved:
//   z even : m2a path (phase-split: 1x1 first, then main+avg; 4 live accs)
//   z odd  : m2b path (LDS 22400 B, [c4][10][35] padded)
// grid (8,32,16), 256 thr / 4 waves; wave -> 2 output rows; 3 blocks/CU.
// ---------------------------------------------------------------------------
__global__ __launch_bounds__(256, 3) void m2ab_kernel(
    const unsigned short* __restrict__ xt,
    const unsigned short* __restrict__ t1g,
    const __hip_bfloat16* __restrict__ Wg,
    const int* __restrict__ och_g,
    const float* __restrict__ biasb,
    float* __restrict__ out)
{
    __shared__ __align__(16) unsigned char smem[43520];

    const int t = threadIdx.x;
    const int lane = t & 63, wv = t >> 6;
    const int i31 = lane & 31, g = lane >> 5;
    const int x0 = blockIdx.x * 32, y0 = blockIdx.y * 8;
    const int zz = blockIdx.z;
    const int b = zz >> 1;

    const int y_0 = y0 + 2 * wv, y_1 = y_0 + 1;      // output rows
    const int r0 = 2 * wv + 1, r1 = r0 + 1;          // halo rows

    if ((zz & 1) == 0) {
        // ================= m2a path =================
        unsigned short* xs = (unsigned short*)smem;   // [c8][10][34] chunks
        {
            u32x4 tmp[11];
            int   jj[11];
            #pragma unroll
            for (int i = 0; i < 11; i++) {
                int j = t + i * 256;
                if (j > 2719) j = 2719;
                jj[i] = j;
                int c = j / 340, rem = j - c * 340, r = rem / 34, p = rem - r * 34;
                size_t src = ((size_t)(b * BROW + y0 + r) * 8 + c) * ROWP + x0 + p;
                tmp[i] = *(const u32x4*)(xt + src * 8);
            }
            #pragma unroll
            for (int i = 0; i < 11; i++)
                *(u32x4*)(xs + (size_t)jj[i] * 8) = tmp[i];
        }
        __syncthreads();

        float* outb = out + (size_t)b * (64 * 65536);

        // ---- phase 1: 1x1 branch (center tap), stored immediately ----
        {
            f32x16 aX0 = zero16(), aX1 = zero16();
            #pragma unroll
            for (int s = 0; s < 4; s++) {
                bf16x8 bx = *(const bf16x8*)(Wg + 22528 + ((s*2+g)*32 + i31) * 8);
                bf16x8 a0 = *(const bf16x8*)(xs + (size_t)(((s*2+g) * 10 + r0) * 34 + i31 + 1) * 8);
                bf16x8 a1 = *(const bf16x8*)(xs + (size_t)(((s*2+g) * 10 + r1) * 34 + i31 + 1) * 8);
                aX0 = MFMA32(a0, bx, aX0);
                aX1 = MFMA32(a1, bx, aX1);
            }
            store4(outb, aX0, och_g, biasb + 64, 32, y_0, x0, i31, g);  // 1x1 -> [32,64)
            store4(outb, aX1, och_g, biasb + 64, 32, y_1, x0, i31, g);
        }

        // ---- phase 2: main 3x3 + avg-as-3x3 (4 live accumulators) ----
        f32x16 aM0 = zero16(), aM1 = zero16();
        f32x16 aG0 = zero16(), aG1 = zero16();
        {
            bf16x8 bg[4];
            #pragma unroll
            for (int s = 0; s < 4; s++)
                bg[s] = *(const bf16x8*)(Wg + 20480 + ((s*2+g)*32 + i31) * 8);
            #pragma unroll
            for (int tap = 0; tap < 9; tap++) {
                int dy = tap / 3 - 1, dx = tap - (tap / 3) * 3 - 1;
                int pbase = i31 + dx + 1;
                #pragma unroll
                for (int s = 0; s < 4; s++) {
                    bf16x8 bm = *(const bf16x8*)(Wg + 2048 + (((tap*4+s)*2+g)*32 + i31) * 8);
                    bf16x8 a0 = *(const bf16x8*)(xs + (size_t)(((s*2+g) * 10 + r0 + dy) * 34 + pbase) * 8);
                    bf16x8 a1 = *(const bf16x8*)(xs + (size_t)(((s*2+g) * 10 + r1 + dy) * 34 + pbase) * 8);
                    aM0 = MFMA32(a0, bm, aM0);
                    aM1 = MFMA32(a1, bm, aM1);
                    aG0 = MFMA32(a0, bg[s], aG0);
                    aG1 = MFMA32(a1, bg[s], aG1);
                }
            }
        }
        store4(outb, aM0, och_g, biasb + 32, 0,  y_0, x0, i31, g);  // main -> [0,32)
        store4(outb, aM1, och_g, biasb + 32, 0,  y_1, x0, i31, g);
        store4avg(outb, aG0, och_g, biasb, y_0, x0, i31, g);        // avg  -> [96,128)
        store4avg(outb, aG1, och_g, biasb, y_1, x0, i31, g);
    } else {
        // ================= m2b path =================
        unsigned short* t1s = (unsigned short*)smem;  // [c4][10][35] chunks (padded)
        #pragma unroll
        for (int i = 0; i < 6; i++) {
            int j = t + i * 256;
            if (j > 1359) j = 1359;
            int c4 = j & 3, pr = j >> 2;
            int r = pr / 34, p = pr - r * 34;
            size_t src = ((size_t)(b * BROW + y0 + r) * ROWP + x0 + p) * 32 + c4 * 8;
            int ci = c4 * 350 + r * 35 + p;
            *(u32x4*)(t1s + (size_t)ci * 8) = *(const u32x4*)(t1g + src);
        }
        __syncthreads();

        float* outb = out + (size_t)b * (64 * 65536);
        f32x16 aC0 = zero16(), aC1 = zero16();
        #pragma unroll
        for (int tap = 0; tap < 9; tap++) {
            int dy = tap / 3 - 1, dx = tap - (tap / 3) * 3 - 1;
            int pbase = i31 + dx + 1;
            #pragma unroll
            for (int s = 0; s < 2; s++) {
                bf16x8 bc = *(const bf16x8*)(Wg + 24576 + (((tap*2+s)*2+g)*32 + i31) * 8);
                bf16x8 a0 = *(const bf16x8*)(t1s + (size_t)((s*2+g) * 350 + (r0 + dy) * 35 + pbase) * 8);
                bf16x8 a1 = *(const bf16x8*)(t1s + (size_t)((s*2+g) * 350 + (r1 + dy) * 35 + pbase) * 8);
                aC0 = MFMA32(a0, bc, aC0);
                aC1 = MFMA32(a1, bc, aC1);
            }
        }
        store4(outb, aC0, och_g, biasb + 96, 64, y_0, x0, i31, g);  // 3x3 -> [64,96)
        store4(outb, aC1, och_g, biasb + 96, 64, y_1, x0, i31, g);
    }
}

// ---------------------------------------------------------------------------
// Fallback: round-3 single fused kernel (r8 weight addressing) for small ws.
// ---------------------------------------------------------------------------
__global__ __launch_bounds__(512, 4) void fused_fallback(
    const float* __restrict__ x,
    const __hip_bfloat16* __restrict__ Wg,
    const int* __restrict__ och_g,
    const float* __restrict__ biasb,
    float* __restrict__ out)
{
    __shared__ __align__(16) unsigned char xs[400 * 128];
    __shared__ __align__(16) unsigned char t1s[340 * 64];

    const int t = threadIdx.x;
    const int lane = t & 63, wv = t >> 6;
    const int i31 = lane & 31, g = lane >> 5;
    const int x0 = blockIdx.x * 32, y0 = blockIdx.y * 8;
    const int b = blockIdx.z;

    const float* xb = x + (size_t)b * (64 * 65536);
    for (int j = t; j < 800; j += 512) {
        int co = j / 100;
        int rem = j - co * 100;
        int row = rem / 10, xq = rem - row * 10;
        int gy = y0 - 1 + row;
        int gx0 = x0 - 4 + 4 * xq;
        bool ok = ((unsigned)gy < 256u) && ((unsigned)gx0 <= 252u);
        const float* p = xb + (size_t)(co * 8) * 65536 + (size_t)gy * 256 + gx0;
        float4 f0 = {0,0,0,0}, f1 = {0,0,0,0}, f2 = {0,0,0,0}, f3 = {0,0,0,0};
        float4 f4 = {0,0,0,0}, f5 = {0,0,0,0}, f6 = {0,0,0,0}, f7 = {0,0,0,0};
        if (ok) {
            f0 = *(const float4*)(p);
            f1 = *(const float4*)(p + 65536);
            f2 = *(const float4*)(p + 131072);
            f3 = *(const float4*)(p + 196608);
            f4 = *(const float4*)(p + 262144);
            f5 = *(const float4*)(p + 327680);
            f6 = *(const float4*)(p + 393216);
            f7 = *(const float4*)(p + 458752);
        }
        const float* fv[8] = {(const float*)&f0, (const float*)&f1, (const float*)&f2,
                              (const float*)&f3, (const float*)&f4, (const float*)&f5,
                              (const float*)&f6, (const float*)&f7};
        #pragma unroll
        for (int u = 0; u < 4; u++) {
            int pos = row * 40 + 4 * xq + u;
            u32x4 w;
            w[0] = (unsigned)f2bf(fv[0][u]) | ((unsigned)f2bf(fv[1][u]) << 16);
            w[1] = (unsigned)f2bf(fv[2][u]) | ((unsigned)f2bf(fv[3][u]) << 16);
            w[2] = (unsigned)f2bf(fv[4][u]) | ((unsigned)f2bf(fv[5][u]) << 16);
            w[3] = (unsigned)f2bf(fv[6][u]) | ((unsigned)f2bf(fv[7][u]) << 16);
            *(u32x4*)(xs + xs_addr(pos, co * 16)) = w;
        }
    }
    __syncthreads();

    {
        bf16x8 bA[4];
        #pragma unroll
        for (int s = 0; s < 4; s++)
            bA[s] = *(const bf16x8*)(Wg + ((s*2+g)*32 + i31) * 8);
        float biasA = biasb[i31];
        for (int mt = wv; mt < 11; mt += 8) {
            int m0 = mt * 32;
            f32x16 acc = zero16();
            int qr = m0 + i31; if (qr > 339) qr = 339;
            int hy = qr / 34, hx = qr - hy * 34;
            int pos = hy * 40 + hx + 3;
            #pragma unroll
            for (int s = 0; s < 4; s++) {
                bf16x8 a = *(const bf16x8*)(xs + xs_addr(pos, s * 32 + g * 16));
                acc = MFMA32(a, bA[s], acc);
            }
            #pragma unroll
            for (int r = 0; r < 16; r++) {
                int q = m0 + (r & 3) + 8 * (r >> 2) + 4 * g;
                if (q < 340) {
                    int hy2 = q / 34, hx2 = q - hy2 * 34;
                    int gy = y0 - 1 + hy2, gx = x0 - 1 + hx2;
                    bool valid = ((unsigned)gy < 256u) && ((unsigned)gx < 256u);
                    float vv = valid ? (acc[r] + biasA) : 0.f;
                    *(unsigned short*)(t1s + t1_addr(q, i31 * 2)) = f2bf(vv);
                }
            }
        }
    }
    __syncthreads();

    float* outb = out + (size_t)b * (64 * 65536);
    const int y = y0 + wv;

    f32x16 aM = zero16(), aG = zero16(), aX = zero16();
    {
        bf16x8 bg[4], bx[4];
        #pragma unroll
        for (int s = 0; s < 4; s++) {
            bg[s] = *(const bf16x8*)(Wg + 20480 + ((s*2+g)*32 + i31) * 8);
            bx[s] = *(const bf16x8*)(Wg + 22528 + ((s*2+g)*32 + i31) * 8);
        }
        for (int tap = 0; tap < 9; tap++) {
            int dy = tap / 3 - 1, dx = tap - (tap / 3) * 3 - 1;
            int pos = (wv + 1 + dy) * 40 + 4 + dx + i31;
            #pragma unroll
            for (int s = 0; s < 4; s++) {
                bf16x8 bm = *(const bf16x8*)(Wg + 2048 + (((tap*4+s)*2+g)*32 + i31) * 8);
                bf16x8 a = *(const bf16x8*)(xs + xs_addr(pos, s * 32 + g * 16));
                aM = MFMA32(a, bm, aM);
                aG = MFMA32(a, bg[s], aG);
                if (tap == 4) aX = MFMA32(a, bx[s], aX);
            }
        }
    }
    store4(outb, aM, och_g, biasb + 32, 0,  y, x0, i31, g);
    store4(outb, aX, och_g, biasb + 64, 32, y, x0, i31, g);
    store4avg(outb, aG, och_g, biasb, y, x0, i31, g);

    f32x16 aC = zero16();
    for (int tap = 0; tap < 9; tap++) {
        int dy = tap / 3 - 1, dx = tap - (tap / 3) * 3 - 1;
        int q = (wv + 1 + dy) * 34 + 1 + dx + i31;
        #pragma unroll
        for (int s = 0; s < 2; s++) {
            bf16x8 bc = *(const bf16x8*)(Wg + 24576 + (((tap*2+s)*2+g)*32 + i31) * 8);
            bf16x8 a = *(const bf16x8*)(t1s + t1_addr(q, s * 32 + g * 16));
            aC = MFMA32(a, bc, aC);
        }
    }
    store4(outb, aC, och_g, biasb + 96, 64, y, x0, i31, g);
}

// ---------------------------------------------------------------------------
extern "C" void kernel_launch(void* const* d_in, const int* in_sizes, int n_in,
                              void* d_out, int out_size, void* d_ws, size_t ws_size,
                              hipStream_t stream)
{
    const float* x        = (const float*)d_in[0];
    const float* w_main   = (const float*)d_in[1];
    const float* bn_main  = (const float*)d_in[2];
    const float* w_1x1    = (const float*)d_in[3];
    const float* bn_1x1   = (const float*)d_in[4];
    const float* w_3x3_1  = (const float*)d_in[5];
    const float* bn_3x3_1 = (const float*)d_in[6];
    const float* w_3x3_2  = (const float*)d_in[7];
    const float* bn_3x3_2 = (const float*)d_in[8];
    const float* w_avg    = (const float*)d_in[9];
    const float* bn_avg_1 = (const float*)d_in[10];
    const float* bn_avg_2 = (const float*)d_in[11];
    const float* c_score  = (const float*)d_in[12];

    int*   och   = (int*)d_ws;
    float* biasb = (float*)((char*)d_ws + 512);
    __hip_bfloat16* wb = (__hip_bfloat16*)((char*)d_ws + 2048);

    prep_kernel<<<4, 256, 0, stream>>>(
        c_score, w_main, bn_main, w_1x1, bn_1x1,
        w_3x3_1, bn_3x3_1, w_3x3_2, bn_3x3_2, w_avg, bn_avg_1, bn_avg_2,
        och, biasb, wb);

    if (ws_size >= WS_NEED) {
        unsigned short* xt  = (unsigned short*)((char*)d_ws + XT_OFF);
        unsigned short* t1g = (unsigned short*)((char*)d_ws + T1_OFF);

        t_kernel<<<dim3(2, 256, 8), 256, 0, stream>>>(x, xt);
        m1_kernel<<<dim3(2, 256, 8), 256, 0, stream>>>(xt, wb, biasb, t1g);
        m2ab_kernel<<<dim3(8, 32, 16), 256, 0, stream>>>(
            xt, t1g, wb, och, biasb, (float*)d_out);
    } else {
        fused_fallback<<<dim3(8, 32, 8), 512, 0, stream>>>(
            x, wb, och, biasb, (float*)d_out);
    }
}